// Round 5
// baseline (228.789 us; speedup 1.0000x reference)
//
#include <hip/hip_runtime.h>
#include <hip/hip_bf16.h>
#include <math.h>
#include <stdint.h>

typedef __bf16 bf16;
typedef __bf16 bf16x8 __attribute__((ext_vector_type(8)));
typedef __bf16 bf16x4 __attribute__((ext_vector_type(4)));
typedef float  f32x4  __attribute__((ext_vector_type(4)));

#define MFMA16(a,b,c) __builtin_amdgcn_mfma_f32_16x16x32_bf16((a),(b),(c),0,0,0)

static constexpr int kB  = 2;
static constexpr int kS  = 2048;
static constexpr int kD  = 1024;
static constexpr int kH  = 16;
static constexpr int kHD = 64;
static constexpr int kM  = kB * kS;         // 4096
// exp(s*0.125) = exp2(s * 0.125 * log2(e)) ; folded into Q at proj epilogue
static constexpr float kExpC = 0.125f * 1.44269504f;

// async global->LDS, 16 B per lane. LDS dest must be the wave-uniform base;
// HW adds lane*16. Global src is per-lane.
__device__ __forceinline__ void gl_lds16(const bf16* g, bf16* l) {
  __builtin_amdgcn_global_load_lds(
      (const __attribute__((address_space(1))) unsigned int*)g,
      (__attribute__((address_space(3))) unsigned int*)l, 16, 0, 0);
}

// ---------------- fp32 -> bf16 conversion (x + 4 weights) + RoPE table ----------------
__global__ void cvt_all(const float* __restrict__ x,
                        const float* __restrict__ wq, const float* __restrict__ wk,
                        const float* __restrict__ wv, const float* __restrict__ wo,
                        bf16* __restrict__ xb,
                        bf16* __restrict__ wqb, bf16* __restrict__ wkb,
                        bf16* __restrict__ wvb, bf16* __restrict__ wob,
                        float2* __restrict__ rtab)
{
  const int i = blockIdx.x * 256 + threadIdx.x;   // float4 index
  const int NX4 = (kM * kD) / 4;                  // 1048576
  const int NW4 = (kD * kD) / 4;                  // 262144 = 2^18
  if (i >= NX4 + 4 * NW4) {                       // RoPE cos/sin table: 2048 x 32
    const int idx = i - (NX4 + 4 * NW4);          // exactly 65536 of these
    const int s = idx >> 5, d = idx & 31;
    const float f = exp2f(-(float)d * 0.4152410118609203f);  // 10000^(-d/32)
    float sn, cs;
    sincosf((float)s * f, &sn, &cs);
    rtab[idx] = make_float2(cs, sn);
    return;
  }
  const float* src; bf16* dst; int off;
  if (i < NX4) { src = x; dst = xb; off = i; }
  else {
    const int j = i - NX4;
    const int seg = j >> 18;
    off = j & (NW4 - 1);
    src = (seg == 0) ? wq : (seg == 1) ? wk : (seg == 2) ? wv : wo;
    dst = (seg == 0) ? wqb : (seg == 1) ? wkb : (seg == 2) ? wvb : wob;
  }
  const float4 v = ((const float4*)src)[off];
  bf16x4 o = { (bf16)v.x, (bf16)v.y, (bf16)v.z, (bf16)v.w };
  ((bf16x4*)dst)[off] = o;
}

// ---------------- 128x128 tile bf16 GEMM core, global_load_lds double-buffer --------
// C = A * B^T. A:[M,K], Bw:[N,K], row-major bf16. BK=32, 256 threads, 2x2 waves.
// T3 minimal 2-phase: ONE barrier per K-step; the next tile's 4 async
// global_load_lds are issued right after the barrier and stay in flight under
// the 16 MFMAs (drained by the next barrier's vmcnt(0)).
__device__ __forceinline__ void gemm_core_128(
    const bf16* __restrict__ A, const bf16* __restrict__ Bw,
    int m0, int n0, int K, bf16* smem, f32x4 acc[4][4])
{
  const int t = threadIdx.x, lane = t & 63, wave = t >> 6;
  const int wm = wave >> 1, wn = wave & 1;
  const int srow = lane >> 2;          // 0..15
  const int scol = (lane & 3) * 8;     // 0,8,16,24
  const bf16* ga0 = A  + (size_t)(m0 + wave * 16 + srow) * K + scol;
  const bf16* ga1 = ga0 + (size_t)64 * K;
  const bf16* gb0 = Bw + (size_t)(n0 + wave * 16 + srow) * K + scol;
  const bf16* gb1 = gb0 + (size_t)64 * K;
  const int woff = wave * 512;

  {  // prologue: stage tile k=0 into buf0
    bf16* lb = smem;
    gl_lds16(ga0, lb + woff);
    gl_lds16(ga1, lb + 2048 + woff);
    gl_lds16(gb0, lb + 4096 + woff);
    gl_lds16(gb1, lb + 6144 + woff);
  }
  int cur = 0;
  for (int k0 = 0; k0 < K; k0 += 32) {
    __syncthreads();   // vmcnt(0) drain: buf[cur] staged; prior reads of buf[cur^1] done
    if (k0 + 32 < K) { // issue next tile early; in flight during MFMA below
      bf16* lb = smem + (cur ^ 1) * 8192;
      gl_lds16(ga0 + k0 + 32, lb + woff);
      gl_lds16(ga1 + k0 + 32, lb + 2048 + woff);
      gl_lds16(gb0 + k0 + 32, lb + 4096 + woff);
      gl_lds16(gb1 + k0 + 32, lb + 6144 + woff);
    }
    const bf16* aT = smem + cur * 8192;
    const bf16* bT = aT + 4096;
    bf16x8 af[4], bfr[4];
#pragma unroll
    for (int i = 0; i < 4; ++i) {
      af[i]  = *(const bf16x8*)(aT + (wm * 64 + i * 16 + (lane & 15)) * 32 + (lane >> 4) * 8);
      bfr[i] = *(const bf16x8*)(bT + (wn * 64 + i * 16 + (lane & 15)) * 32 + (lane >> 4) * 8);
    }
#pragma unroll
    for (int i = 0; i < 4; ++i)
#pragma unroll
      for (int j = 0; j < 4; ++j)
        acc[i][j] = MFMA16(af[i], bfr[j], acc[i][j]);
    cur ^= 1;
  }
}

// ---------------- QKV projection + RoPE epilogue; V written pre-transposed ----------------
__global__ __launch_bounds__(256, 4) void proj_qkv(
    const bf16* __restrict__ xb,
    const bf16* __restrict__ wqb, const bf16* __restrict__ wkb, const bf16* __restrict__ wvb,
    bf16* __restrict__ Qb, bf16* __restrict__ Kb, bf16* __restrict__ Vt,
    const float2* __restrict__ rtab)
{
  __shared__ __align__(16) bf16 smem[16384];   // 32 KB: gemm dbuf, then V-transpose
  const int z = blockIdx.z;
  const bf16* Ww = (z == 0) ? wqb : (z == 1) ? wkb : wvb;
  const int m0 = blockIdx.x * 128, n0 = blockIdx.y * 128;
  f32x4 acc[4][4] = {};
  gemm_core_128(xb, Ww, m0, n0, kD, smem, acc);

  const int lane = threadIdx.x & 63, wave = threadIdx.x >> 6;
  const int wm = wave >> 1, wn = wave & 1, quad = lane >> 4, lc = lane & 15;
  const int hh = (n0 >> 6) + wn;     // head index; wave's 64-col span == one head
  if (z == 2) {                      // V: transpose via LDS, store [bh][d][s] coalesced
    __syncthreads();                 // all waves done reading gemm smem
    const int t = threadIdx.x;
    const int row = t >> 1;          // n = head*64 + d, 0..127
    const int coff = (t & 1) * 32;
    const int bidx = m0 >> 11;
    const int hh2 = (n0 >> 6) + (row >> 6);
    const int d = row & 63;
    bf16* vtr = smem;                // [128 n][72] per pass (m-half)
#pragma unroll
    for (int p = 0; p < 2; ++p) {
      if (p) __syncthreads();        // pass-0 reads done before overwrite
      if (wm == p) {                 // waves owning m in [p*64, p*64+64)
#pragma unroll
        for (int i = 0; i < 4; ++i)
#pragma unroll
          for (int j = 0; j < 4; ++j) {
            bf16x4 pk;
#pragma unroll
            for (int r = 0; r < 4; ++r) pk[r] = (bf16)acc[i][j][r];
            *(bf16x4*)&vtr[(wn * 64 + j * 16 + lc) * 72 + i * 16 + quad * 4] = pk;
          }
      }
      __syncthreads();
      bf16* dst = Vt + ((size_t)(bidx * kH + hh2) * kHD + d) * kS
                     + (m0 & 2047) + p * 64 + coff;
#pragma unroll
      for (int u = 0; u < 4; ++u)
        *(uint4*)(dst + u * 8) = *(const uint4*)&vtr[row * 72 + coff + u * 8];
    }
  } else {                           // Q/K: RoPE in-register (pair d with d+32)
    bf16* Op = (z == 0) ? Qb : Kb;
    const float f = (z == 0) ? kExpC : 1.0f;   // fold softmax scale into Q
#pragma unroll
    for (int j = 0; j < 2; ++j) {
      const int d = j * 16 + lc;     // 0..31
#pragma unroll
      for (int i = 0; i < 4; ++i)
#pragma unroll
        for (int r = 0; r < 4; ++r) {
          const int m = m0 + wm * 64 + i * 16 + quad * 4 + r;
          const int bidx = m >> 11, s = m & 2047;
          const float2 cs = rtab[s * 32 + d];
          const float v0 = acc[i][j][r], v1 = acc[i][j + 2][r];
          bf16* dst = Op + ((size_t)(bidx * kH + hh) * kS + s) * kHD;
          dst[d]      = (bf16)((v0 * cs.x - v1 * cs.y) * f);
          dst[d + 32] = (bf16)((v1 * cs.x + v0 * cs.y) * f);
        }
    }
  }
}

// ---------------- flash attention v5: T14 async-STAGE split --------------------------
// r4 post-mortem: vT-132 cut conflicts 7.34M->3.15M but dur 49.2->51.8 — conflicts
// were NOT critical path; setprio suspected negative (barrier-lockstep block ==
// m190's GEMM regime). Removed setprio.
// The serial cost is staging: global L2-latency loads sit between the two
// barriers, un-overlapped. T14 split (guide §6 G15, +17% attn in m214v27):
// hold tile kt+1 in 8 uint4 regs, issue its loads right after barrier2 so they
// fly under compute; regs->LDS is a short write burst between barriers.
// Traffic is IDENTICAL to r1/r4 (the r2/r3 lesson: never raise traffic).
// VGPR 92+32 ~= 124, far under the 2-block budget — no spill (watch WRITE_SIZE).
__global__ __launch_bounds__(256, 2) void attn(
    const bf16* __restrict__ Qb, const bf16* __restrict__ Kb,
    const bf16* __restrict__ Vt, bf16* __restrict__ Ob)
{
  __shared__ __align__(16) bf16 kT[128 * 72];
  __shared__ __align__(16) bf16 vT[64 * 132];
  const int t = threadIdx.x, lane = t & 63, wave = t >> 6;
  const int quad = lane >> 4, lc = lane & 15;
  const int bid = blockIdx.x;
  const int qt = (bid >> 3) & 15;
  const int bh = (bid & 7) * 4 + (bid >> 7);     // XCD-locality decode
  const size_t base = (size_t)bh * kS * kHD;
  const bf16* Qp = Qb + base + (size_t)qt * 128 * kHD;
  const bf16* Kp = Kb + base;
  const bf16* Vp = Vt + base;                     // [d][s]

  // Q fragments (B-operand layout), in registers for the whole kernel
  bf16x8 qf[2][2];
#pragma unroll
  for (int tm = 0; tm < 2; ++tm)
#pragma unroll
    for (int ks = 0; ks < 2; ++ks)
      qf[tm][ks] = *(const bf16x8*)(Qp + (wave * 32 + tm * 16 + lc) * kHD + ks * 32 + quad * 8);

  f32x4 oacc[2][4] = {};
  f32x4 lacc[2] = {};
  const bf16 one = (bf16)1.0f;
  const bf16x8 ones = { one, one, one, one, one, one, one, one };

  // staging: K: 2 threads/row, 64 B each. V^T: thread (d=t>>2, c=t&3), 64 B each.
  const int srow = t >> 1, shalf = (t & 1) * 32;
  const int vd = t >> 2, vc = t & 3;
  const bf16* ksrc0 = Kp + (size_t)srow * kHD + shalf;
  const bf16* vsrc0 = Vp + (size_t)vd * kS + vc * 32;

  uint4 krg[4], vrg[4];
#pragma unroll
  for (int u = 0; u < 4; ++u) {                   // prologue: tile 0 -> regs
    krg[u] = *(const uint4*)(ksrc0 + u * 8);
    vrg[u] = *(const uint4*)(vsrc0 + kS * 0 + u * 8);
  }
  // note: vsrc advances along the s axis (contiguous), ksrc along rows (x kHD)

  for (int kt = 0; kt < kS / 128; ++kt) {
    __syncthreads();                              // prior tile's readers done
#pragma unroll
    for (int u = 0; u < 4; ++u) {
      *(uint4*)&kT[srow * 72 + shalf + u * 8] = krg[u];
      *(uint4*)&vT[vd * 132 + vc * 32 + u * 8] = vrg[u];
    }
    __syncthreads();                              // tile visible
    if (kt + 1 < kS / 128) {                      // issue kt+1 loads; fly under compute
      const bf16* kn = ksrc0 + (size_t)(kt + 1) * 128 * kHD;
      const bf16* vn = vsrc0 + (kt + 1) * 128;
#pragma unroll
      for (int u = 0; u < 4; ++u) {
        krg[u] = *(const uint4*)(kn + u * 8);
        vrg[u] = *(const uint4*)(vn + u * 8);
      }
    }

    // K fragments for the whole tile
    bf16x8 kf[8][2];
#pragma unroll
    for (int nk = 0; nk < 8; ++nk)
#pragma unroll
      for (int ks = 0; ks < 2; ++ks)
        kf[nk][ks] = *(const bf16x8*)&kT[(nk * 16 + lc) * 72 + ks * 32 + quad * 8];

    // S^T = K Q^T ; p = exp2(s) packed straight into A-fragments (no LDS!)
    bf16x8 pfrag[2][4];
#pragma unroll
    for (int tm = 0; tm < 2; ++tm) {
      f32x4 sc[8] = {};
#pragma unroll
      for (int nk = 0; nk < 8; ++nk) {
        sc[nk] = MFMA16(kf[nk][0], qf[tm][0], sc[nk]);
        sc[nk] = MFMA16(kf[nk][1], qf[tm][1], sc[nk]);
      }
#pragma unroll
      for (int kp = 0; kp < 4; ++kp) {
        bf16x8 p;
#pragma unroll
        for (int j = 0; j < 4; ++j) {
          p[j]     = (bf16)__builtin_amdgcn_exp2f(sc[2 * kp][j]);
          p[j + 4] = (bf16)__builtin_amdgcn_exp2f(sc[2 * kp + 1][j]);
        }
        pfrag[tm][kp] = p;
      }
    }

    // row sums via ones-MFMA (same remapped key order on both operands)
#pragma unroll
    for (int kp = 0; kp < 4; ++kp)
#pragma unroll
      for (int tm = 0; tm < 2; ++tm)
        lacc[tm] = MFMA16(pfrag[tm][kp], ones, lacc[tm]);

    // O += P V : V fragment = two b64 reads matching the remapped key order
#pragma unroll
    for (int nd = 0; nd < 4; ++nd)
#pragma unroll
      for (int kp = 0; kp < 4; ++kp) {
        const bf16x4 lo = *(const bf16x4*)&vT[(nd * 16 + lc) * 132 + kp * 32 + quad * 4];
        const bf16x4 hi = *(const bf16x4*)&vT[(nd * 16 + lc) * 132 + kp * 32 + 16 + quad * 4];
        const bf16x8 vfr = __builtin_shufflevector(lo, hi, 0, 1, 2, 3, 4, 5, 6, 7);
#pragma unroll
        for (int tm = 0; tm < 2; ++tm)
          oacc[tm][nd] = MFMA16(pfrag[tm][kp], vfr, oacc[tm][nd]);
      }
  }

  // normalize + store O as bf16 in [B,S,D] layout for the output GEMM
  const int b = bh >> 4, h = bh & 15;
#pragma unroll
  for (int tm = 0; tm < 2; ++tm)
#pragma unroll
    for (int r = 0; r < 4; ++r) {
      const float inv = 1.0f / lacc[tm][r];
      const int s = qt * 128 + wave * 32 + tm * 16 + quad * 4 + r;
      bf16* dst = Ob + ((size_t)(b * kS + s)) * kD + h * kHD;
#pragma unroll
      for (int nd = 0; nd < 4; ++nd)
        dst[nd * 16 + lc] = (bf16)(oacc[tm][nd][r] * inv);
    }
}

// ---------------- output projection (fp32 epilogue) ----------------
__global__ __launch_bounds__(256, 4) void out_proj(
    const bf16* __restrict__ Ab, const bf16* __restrict__ wob, float* __restrict__ Cout)
{
  __shared__ __align__(16) bf16 smem[16384];   // 32 KB gemm dbuf
  const int m0 = blockIdx.x * 128, n0 = blockIdx.y * 128;
  f32x4 acc[4][4] = {};
  gemm_core_128(Ab, wob, m0, n0, kD, smem, acc);
  const int lane = threadIdx.x & 63, wave = threadIdx.x >> 6;
  const int wm = wave >> 1, wn = wave & 1, quad = lane >> 4, lc = lane & 15;
#pragma unroll
  for (int i = 0; i < 4; ++i)
#pragma unroll
    for (int r = 0; r < 4; ++r) {
      const int m = m0 + wm * 64 + i * 16 + quad * 4 + r;
#pragma unroll
      for (int j = 0; j < 4; ++j)
        Cout[(size_t)m * kD + n0 + wn * 64 + j * 16 + lc] = acc[i][j][r];
    }
}

extern "C" void kernel_launch(void* const* d_in, const int* in_sizes, int n_in,
                              void* d_out, int out_size, void* d_ws, size_t ws_size,
                              hipStream_t stream)
{
  const float* x  = (const float*)d_in[0];
  const float* wq = (const float*)d_in[1];
  const float* wk = (const float*)d_in[2];
  const float* wv = (const float*)d_in[3];
  const float* wo = (const float*)d_in[4];
  float* out = (float*)d_out;

  char* ws = (char*)d_ws;
  const size_t MB = 1024 * 1024;
  if (ws_size < 57 * MB) return;
  bf16* xb  = (bf16*)(ws + 0 * MB);   // 8 MB
  bf16* wqb = (bf16*)(ws + 8 * MB);   // 2 MB each
  bf16* wkb = (bf16*)(ws + 10 * MB);
  bf16* wvb = (bf16*)(ws + 12 * MB);
  bf16* wob = (bf16*)(ws + 14 * MB);
  bf16* Qb  = (bf16*)(ws + 16 * MB);  // 8 MB each, [B*H][S][64]
  bf16* Kb  = (bf16*)(ws + 24 * MB);
  bf16* Ob  = (bf16*)(ws + 40 * MB);  // 8 MB, [B,S,D]
  float2* rtab = (float2*)(ws + 48 * MB);  // 512 KB RoPE table
  bf16* Vtp = (bf16*)(ws + 49 * MB);  // 8 MB, V transposed [B*H][64][S]

  cvt_all<<<8448, 256, 0, stream>>>(x, wq, wk, wv, wo, xb, wqb, wkb, wvb, wob, rtab);
  proj_qkv<<<dim3(32, 8, 3), 256, 0, stream>>>(xb, wqb, wkb, wvb, Qb, Kb, Vtp, rtab);
  attn<<<dim3(512), 256, 0, stream>>>(Qb, Kb, Vtp, Ob);
  out_proj<<<dim3(32, 8), 256, 0, stream>>>(Ob, wob, out);
}

// Round 6
// 182.541 us; speedup vs baseline: 1.2534x; 1.2534x over previous
//
#include <hip/hip_runtime.h>
#include <hip/hip_bf16.h>
#include <math.h>
#include <stdint.h>

typedef __bf16 bf16;
typedef __bf16 bf16x8 __attribute__((ext_vector_type(8)));
typedef __bf16 bf16x4 __attribute__((ext_vector_type(4)));
typedef float  f32x4  __attribute__((ext_vector_type(4)));

#define MFMA16(a,b,c) __builtin_amdgcn_mfma_f32_16x16x32_bf16((a),(b),(c),0,0,0)

static constexpr int kB  = 2;
static constexpr int kS  = 2048;
static constexpr int kD  = 1024;
static constexpr int kH  = 16;
static constexpr int kHD = 64;
static constexpr int kM  = kB * kS;         // 4096
// exp(s*0.125) = exp2(s * 0.125 * log2(e)) ; folded into Q at proj epilogue
static constexpr float kExpC = 0.125f * 1.44269504f;

// async global->LDS, 16 B per lane. LDS dest must be the wave-uniform base;
// HW adds lane*16. Global src is per-lane.
__device__ __forceinline__ void gl_lds16(const bf16* g, bf16* l) {
  __builtin_amdgcn_global_load_lds(
      (const __attribute__((address_space(1))) unsigned int*)g,
      (__attribute__((address_space(3))) unsigned int*)l, 16, 0, 0);
}

// ---------------- fp32 -> bf16 conversion (x + 4 weights) + RoPE table ----------------
__global__ void cvt_all(const float* __restrict__ x,
                        const float* __restrict__ wq, const float* __restrict__ wk,
                        const float* __restrict__ wv, const float* __restrict__ wo,
                        bf16* __restrict__ xb,
                        bf16* __restrict__ wqb, bf16* __restrict__ wkb,
                        bf16* __restrict__ wvb, bf16* __restrict__ wob,
                        float2* __restrict__ rtab)
{
  const int i = blockIdx.x * 256 + threadIdx.x;   // float4 index
  const int NX4 = (kM * kD) / 4;                  // 1048576
  const int NW4 = (kD * kD) / 4;                  // 262144 = 2^18
  if (i >= NX4 + 4 * NW4) {                       // RoPE cos/sin table: 2048 x 32
    const int idx = i - (NX4 + 4 * NW4);          // exactly 65536 of these
    const int s = idx >> 5, d = idx & 31;
    const float f = exp2f(-(float)d * 0.4152410118609203f);  // 10000^(-d/32)
    float sn, cs;
    sincosf((float)s * f, &sn, &cs);
    rtab[idx] = make_float2(cs, sn);
    return;
  }
  const float* src; bf16* dst; int off;
  if (i < NX4) { src = x; dst = xb; off = i; }
  else {
    const int j = i - NX4;
    const int seg = j >> 18;
    off = j & (NW4 - 1);
    src = (seg == 0) ? wq : (seg == 1) ? wk : (seg == 2) ? wv : wo;
    dst = (seg == 0) ? wqb : (seg == 1) ? wkb : (seg == 2) ? wvb : wob;
  }
  const float4 v = ((const float4*)src)[off];
  bf16x4 o = { (bf16)v.x, (bf16)v.y, (bf16)v.z, (bf16)v.w };
  ((bf16x4*)dst)[off] = o;
}

// ---------------- 128x128 tile bf16 GEMM core, global_load_lds double-buffer --------
// C = A * B^T. A:[M,K], Bw:[N,K], row-major bf16. BK=32, 256 threads, 2x2 waves.
// T3 minimal 2-phase: ONE barrier per K-step; the next tile's 4 async
// global_load_lds are issued right after the barrier and stay in flight under
// the 16 MFMAs (drained by the next barrier's vmcnt(0)).
__device__ __forceinline__ void gemm_core_128(
    const bf16* __restrict__ A, const bf16* __restrict__ Bw,
    int m0, int n0, int K, bf16* smem, f32x4 acc[4][4])
{
  const int t = threadIdx.x, lane = t & 63, wave = t >> 6;
  const int wm = wave >> 1, wn = wave & 1;
  const int srow = lane >> 2;          // 0..15
  const int scol = (lane & 3) * 8;     // 0,8,16,24
  const bf16* ga0 = A  + (size_t)(m0 + wave * 16 + srow) * K + scol;
  const bf16* ga1 = ga0 + (size_t)64 * K;
  const bf16* gb0 = Bw + (size_t)(n0 + wave * 16 + srow) * K + scol;
  const bf16* gb1 = gb0 + (size_t)64 * K;
  const int woff = wave * 512;

  {  // prologue: stage tile k=0 into buf0
    bf16* lb = smem;
    gl_lds16(ga0, lb + woff);
    gl_lds16(ga1, lb + 2048 + woff);
    gl_lds16(gb0, lb + 4096 + woff);
    gl_lds16(gb1, lb + 6144 + woff);
  }
  int cur = 0;
  for (int k0 = 0; k0 < K; k0 += 32) {
    __syncthreads();   // vmcnt(0) drain: buf[cur] staged; prior reads of buf[cur^1] done
    if (k0 + 32 < K) { // issue next tile early; in flight during MFMA below
      bf16* lb = smem + (cur ^ 1) * 8192;
      gl_lds16(ga0 + k0 + 32, lb + woff);
      gl_lds16(ga1 + k0 + 32, lb + 2048 + woff);
      gl_lds16(gb0 + k0 + 32, lb + 4096 + woff);
      gl_lds16(gb1 + k0 + 32, lb + 6144 + woff);
    }
    const bf16* aT = smem + cur * 8192;
    const bf16* bT = aT + 4096;
    bf16x8 af[4], bfr[4];
#pragma unroll
    for (int i = 0; i < 4; ++i) {
      af[i]  = *(const bf16x8*)(aT + (wm * 64 + i * 16 + (lane & 15)) * 32 + (lane >> 4) * 8);
      bfr[i] = *(const bf16x8*)(bT + (wn * 64 + i * 16 + (lane & 15)) * 32 + (lane >> 4) * 8);
    }
#pragma unroll
    for (int i = 0; i < 4; ++i)
#pragma unroll
      for (int j = 0; j < 4; ++j)
        acc[i][j] = MFMA16(af[i], bfr[j], acc[i][j]);
    cur ^= 1;
  }
}

// ---------------- QKV projection + RoPE epilogue; V written pre-transposed ----------------
__global__ __launch_bounds__(256, 4) void proj_qkv(
    const bf16* __restrict__ xb,
    const bf16* __restrict__ wqb, const bf16* __restrict__ wkb, const bf16* __restrict__ wvb,
    bf16* __restrict__ Qb, bf16* __restrict__ Kb, bf16* __restrict__ Vt,
    const float2* __restrict__ rtab)
{
  __shared__ __align__(16) bf16 smem[16384];   // 32 KB: gemm dbuf, then V-transpose
  const int z = blockIdx.z;
  const bf16* Ww = (z == 0) ? wqb : (z == 1) ? wkb : wvb;
  const int m0 = blockIdx.x * 128, n0 = blockIdx.y * 128;
  f32x4 acc[4][4] = {};
  gemm_core_128(xb, Ww, m0, n0, kD, smem, acc);

  const int lane = threadIdx.x & 63, wave = threadIdx.x >> 6;
  const int wm = wave >> 1, wn = wave & 1, quad = lane >> 4, lc = lane & 15;
  const int hh = (n0 >> 6) + wn;     // head index; wave's 64-col span == one head
  if (z == 2) {                      // V: transpose via LDS, store [bh][d][s] coalesced
    __syncthreads();                 // all waves done reading gemm smem
    const int t = threadIdx.x;
    const int row = t >> 1;          // n = head*64 + d, 0..127
    const int coff = (t & 1) * 32;
    const int bidx = m0 >> 11;
    const int hh2 = (n0 >> 6) + (row >> 6);
    const int d = row & 63;
    bf16* vtr = smem;                // [128 n][72] per pass (m-half)
#pragma unroll
    for (int p = 0; p < 2; ++p) {
      if (p) __syncthreads();        // pass-0 reads done before overwrite
      if (wm == p) {                 // waves owning m in [p*64, p*64+64)
#pragma unroll
        for (int i = 0; i < 4; ++i)
#pragma unroll
          for (int j = 0; j < 4; ++j) {
            bf16x4 pk;
#pragma unroll
            for (int r = 0; r < 4; ++r) pk[r] = (bf16)acc[i][j][r];
            *(bf16x4*)&vtr[(wn * 64 + j * 16 + lc) * 72 + i * 16 + quad * 4] = pk;
          }
      }
      __syncthreads();
      bf16* dst = Vt + ((size_t)(bidx * kH + hh2) * kHD + d) * kS
                     + (m0 & 2047) + p * 64 + coff;
#pragma unroll
      for (int u = 0; u < 4; ++u)
        *(uint4*)(dst + u * 8) = *(const uint4*)&vtr[row * 72 + coff + u * 8];
    }
  } else {                           // Q/K: RoPE in-register (pair d with d+32)
    bf16* Op = (z == 0) ? Qb : Kb;
    const float f = (z == 0) ? kExpC : 1.0f;   // fold softmax scale into Q
#pragma unroll
    for (int j = 0; j < 2; ++j) {
      const int d = j * 16 + lc;     // 0..31
#pragma unroll
      for (int i = 0; i < 4; ++i)
#pragma unroll
        for (int r = 0; r < 4; ++r) {
          const int m = m0 + wm * 64 + i * 16 + quad * 4 + r;
          const int bidx = m >> 11, s = m & 2047;
          const float2 cs = rtab[s * 32 + d];
          const float v0 = acc[i][j][r], v1 = acc[i][j + 2][r];
          bf16* dst = Op + ((size_t)(bidx * kH + hh) * kS + s) * kHD;
          dst[d]      = (bf16)((v0 * cs.x - v1 * cs.y) * f);
          dst[d + 32] = (bf16)((v1 * cs.x + v0 * cs.y) * f);
        }
    }
  }
}

// ---------------- flash attention v6: global_load_lds double-buffered K/V ----------
// r5 post-mortem: register-resident cross-barrier prefetch (T14) spilled AGAIN
// (WRITE_SIZE 8->105 MB, dur 2x) — twice-refuted on this kernel, never reintroduce.
// The staging latency diagnosis stands (MfmaUtil ~30%, staging serial between
// barriers). Correct primitive: global_load_lds dbuf (T3) — no dest VGPRs exist,
// nothing can spill; DMA flies under the whole compute phase; ONE barrier/tile
// (its vmcnt(0) drain is the handoff), exactly like the proven gemm_core_128.
// gl_lds needs LINEAR LDS dests, so padded strides are replaced by rule-21
// XOR swizzles (linear dest + inverse-swizzled global SOURCE + swizzled READ):
//   K [128][64]: lane l of issue i fetches row i*8+(l>>3), colblk (l&7)^(l>>3);
//     read colblk (ks*4+quad)^(row&7) -> b128 phases hit 8 distinct bank-quads.
//   V [64][128]: lane l of issue i fetches row i*4+(l>>4), colblk16
//     (l&15)^((i&1)*4+(l>>4)); read blk (kp*4+hi*2+(quad>>1))^(row&7) ->
//     b64 phases 2-way only (free, m136).
// Traffic byte-identical to r1 (r2/r3 lesson: never raise traffic).
// LDS 64 KB x 2 blocks = 128 KB < 160 KB. Datapath unchanged from 49.2 us r1.
__global__ __launch_bounds__(256, 2) void attn(
    const bf16* __restrict__ Qb, const bf16* __restrict__ Kb,
    const bf16* __restrict__ Vt, bf16* __restrict__ Ob)
{
  __shared__ __align__(16) bf16 kT2[2][128 * 64];
  __shared__ __align__(16) bf16 vT2[2][64 * 128];
  const int t = threadIdx.x, lane = t & 63, wave = t >> 6;
  const int quad = lane >> 4, lc = lane & 15;
  const int bid = blockIdx.x;
  const int qt = (bid >> 3) & 15;
  const int bh = (bid & 7) * 4 + (bid >> 7);     // XCD-locality decode
  const size_t base = (size_t)bh * kS * kHD;
  const bf16* Qp = Qb + base + (size_t)qt * 128 * kHD;
  const bf16* Kp = Kb + base;
  const bf16* Vp = Vt + base;                     // [d][s]

  // Q fragments (B-operand layout), in registers for the whole kernel
  bf16x8 qf[2][2];
#pragma unroll
  for (int tm = 0; tm < 2; ++tm)
#pragma unroll
    for (int ks = 0; ks < 2; ++ks)
      qf[tm][ks] = *(const bf16x8*)(Qp + (wave * 32 + tm * 16 + lc) * kHD + ks * 32 + quad * 8);

  f32x4 oacc[2][4] = {};
  f32x4 lacc[2] = {};
  const bf16 one = (bf16)1.0f;
  const bf16x8 ones = { one, one, one, one, one, one, one, one };

  // staging sources (pre-swizzled per-lane global addresses, rule 21)
  const bf16* kst  = Kp + (size_t)(wave * 32 + (lane >> 3)) * kHD
                        + 8 * ((lane & 7) ^ (lane >> 3));
  const bf16* vst0 = Vp + (size_t)(wave * 16 + (lane >> 4)) * kS
                        + 8 * ((lane & 15) ^ (lane >> 4));
  const bf16* vst1 = Vp + (size_t)(wave * 16 + (lane >> 4)) * kS
                        + 8 * (((lane & 15) ^ (lane >> 4)) ^ 4);
  const int ldsb = wave * 2048;                   // elems; + i*512 per issue

  // prologue: stage tile 0 into buf 0 (4 K-issues + 4 V-issues per wave)
#pragma unroll
  for (int i = 0; i < 4; ++i) {
    gl_lds16(kst + (size_t)i * 8 * kHD, &kT2[0][ldsb + i * 512]);
    gl_lds16(((i & 1) ? vst1 : vst0) + (size_t)i * 4 * kS, &vT2[0][ldsb + i * 512]);
  }

  int cur = 0;
  for (int kt = 0; kt < kS / 128; ++kt) {
    __syncthreads();   // vmcnt(0) drain: buf[cur] staged; prior reads of buf[cur^1] done
    if (kt + 1 < kS / 128) {         // issue kt+1 DMA; in flight under all compute below
      const bf16* kn = kst + (size_t)(kt + 1) * 128 * kHD;
      const int vo = (kt + 1) * 128;
#pragma unroll
      for (int i = 0; i < 4; ++i) {
        gl_lds16(kn + (size_t)i * 8 * kHD, &kT2[cur ^ 1][ldsb + i * 512]);
        gl_lds16(((i & 1) ? vst1 : vst0) + (size_t)i * 4 * kS + vo,
                 &vT2[cur ^ 1][ldsb + i * 512]);
      }
    }
    const bf16* kbuf = kT2[cur];
    const bf16* vbuf = vT2[cur];

    // K fragments for the whole tile (swizzled read, conflict-free)
    bf16x8 kf[8][2];
#pragma unroll
    for (int nk = 0; nk < 8; ++nk)
#pragma unroll
      for (int ks = 0; ks < 2; ++ks)
        kf[nk][ks] = *(const bf16x8*)&kbuf[(nk * 16 + lc) * 64
                                           + 8 * ((ks * 4 + quad) ^ (lane & 7))];

    // S^T = K Q^T ; p = exp2(s) packed straight into A-fragments (no LDS!)
    bf16x8 pfrag[2][4];
#pragma unroll
    for (int tm = 0; tm < 2; ++tm) {
      f32x4 sc[8] = {};
#pragma unroll
      for (int nk = 0; nk < 8; ++nk) {
        sc[nk] = MFMA16(kf[nk][0], qf[tm][0], sc[nk]);
        sc[nk] = MFMA16(kf[nk][1], qf[tm][1], sc[nk]);
      }
#pragma unroll
      for (int kp = 0; kp < 4; ++kp) {
        bf16x8 p;
#pragma unroll
        for (int j = 0; j < 4; ++j) {
          p[j]     = (bf16)__builtin_amdgcn_exp2f(sc[2 * kp][j]);
          p[j + 4] = (bf16)__builtin_amdgcn_exp2f(sc[2 * kp + 1][j]);
        }
        pfrag[tm][kp] = p;
      }
    }

    // row sums via ones-MFMA (same remapped key order on both operands)
#pragma unroll
    for (int kp = 0; kp < 4; ++kp)
#pragma unroll
      for (int tm = 0; tm < 2; ++tm)
        lacc[tm] = MFMA16(pfrag[tm][kp], ones, lacc[tm]);

    // O += P V : V fragment = two b64 swizzled reads matching remapped key order
#pragma unroll
    for (int nd = 0; nd < 4; ++nd)
#pragma unroll
      for (int kp = 0; kp < 4; ++kp) {
        const int r = nd * 16 + lc;
        const bf16x4 lo = *(const bf16x4*)&vbuf[r * 128
            + (((kp * 4 + (quad >> 1)) ^ (lane & 7)) * 8 + (quad & 1) * 4)];
        const bf16x4 hi = *(const bf16x4*)&vbuf[r * 128
            + (((kp * 4 + 2 + (quad >> 1)) ^ (lane & 7)) * 8 + (quad & 1) * 4)];
        const bf16x8 vfr = __builtin_shufflevector(lo, hi, 0, 1, 2, 3, 4, 5, 6, 7);
#pragma unroll
        for (int tm = 0; tm < 2; ++tm)
          oacc[tm][nd] = MFMA16(pfrag[tm][kp], vfr, oacc[tm][nd]);
      }
    cur ^= 1;
  }

  // normalize + store O as bf16 in [B,S,D] layout for the output GEMM
  const int b = bh >> 4, h = bh & 15;
#pragma unroll
  for (int tm = 0; tm < 2; ++tm)
#pragma unroll
    for (int r = 0; r < 4; ++r) {
      const float inv = 1.0f / lacc[tm][r];
      const int s = qt * 128 + wave * 32 + tm * 16 + quad * 4 + r;
      bf16* dst = Ob + ((size_t)(b * kS + s)) * kD + h * kHD;
#pragma unroll
      for (int nd = 0; nd < 4; ++nd)
        dst[nd * 16 + lc] = (bf16)(oacc[tm][nd][r] * inv);
    }
}

// ---------------- output projection (fp32 epilogue) ----------------
__global__ __launch_bounds__(256, 4) void out_proj(
    const bf16* __restrict__ Ab, const bf16* __restrict__ wob, float* __restrict__ Cout)
{
  __shared__ __align__(16) bf16 smem[16384];   // 32 KB gemm dbuf
  const int m0 = blockIdx.x * 128, n0 = blockIdx.y * 128;
  f32x4 acc[4][4] = {};
  gemm_core_128(Ab, wob, m0, n0, kD, smem, acc);
  const int lane = threadIdx.x & 63, wave = threadIdx.x >> 6;
  const int wm = wave >> 1, wn = wave & 1, quad = lane >> 4, lc = lane & 15;
#pragma unroll
  for (int i = 0; i < 4; ++i)
#pragma unroll
    for (int r = 0; r < 4; ++r) {
      const int m = m0 + wm * 64 + i * 16 + quad * 4 + r;
#pragma unroll
      for (int j = 0; j < 4; ++j)
        Cout[(size_t)m * kD + n0 + wn * 64 + j * 16 + lc] = acc[i][j][r];
    }
}

extern "C" void kernel_launch(void* const* d_in, const int* in_sizes, int n_in,
                              void* d_out, int out_size, void* d_ws, size_t ws_size,
                              hipStream_t stream)
{
  const float* x  = (const float*)d_in[0];
  const float* wq = (const float*)d_in[1];
  const float* wk = (const float*)d_in[2];
  const float* wv = (const float*)d_in[3];
  const float* wo = (const float*)d_in[4];
  float* out = (float*)d_out;

  char* ws = (char*)d_ws;
  const size_t MB = 1024 * 1024;
  if (ws_size < 57 * MB) return;
  bf16* xb  = (bf16*)(ws + 0 * MB);   // 8 MB
  bf16* wqb = (bf16*)(ws + 8 * MB);   // 2 MB each
  bf16* wkb = (bf16*)(ws + 10 * MB);
  bf16* wvb = (bf16*)(ws + 12 * MB);
  bf16* wob = (bf16*)(ws + 14 * MB);
  bf16* Qb  = (bf16*)(ws + 16 * MB);  // 8 MB each, [B*H][S][64]
  bf16* Kb  = (bf16*)(ws + 24 * MB);
  bf16* Ob  = (bf16*)(ws + 40 * MB);  // 8 MB, [B,S,D]
  float2* rtab = (float2*)(ws + 48 * MB);  // 512 KB RoPE table
  bf16* Vtp = (bf16*)(ws + 49 * MB);  // 8 MB, V transposed [B*H][64][S]

  cvt_all<<<8448, 256, 0, stream>>>(x, wq, wk, wv, wo, xb, wqb, wkb, wvb, wob, rtab);
  proj_qkv<<<dim3(32, 8, 3), 256, 0, stream>>>(xb, wqb, wkb, wvb, Qb, Kb, Vtp, rtab);
  attn<<<dim3(512), 256, 0, stream>>>(Qb, Kb, Vtp, Ob);
  out_proj<<<dim3(32, 8), 256, 0, stream>>>(Ob, wob, out);
}

// Round 7
// 181.476 us; speedup vs baseline: 1.2607x; 1.0059x over previous
//
#include <hip/hip_runtime.h>
#include <hip/hip_bf16.h>
#include <math.h>
#include <stdint.h>

typedef __bf16 bf16;
typedef __bf16 bf16x8 __attribute__((ext_vector_type(8)));
typedef __bf16 bf16x4 __attribute__((ext_vector_type(4)));
typedef float  f32x4  __attribute__((ext_vector_type(4)));

#define MFMA16(a,b,c) __builtin_amdgcn_mfma_f32_16x16x32_bf16((a),(b),(c),0,0,0)

static constexpr int kB  = 2;
static constexpr int kS  = 2048;
static constexpr int kD  = 1024;
static constexpr int kH  = 16;
static constexpr int kHD = 64;
static constexpr int kM  = kB * kS;         // 4096
// exp(s*0.125) = exp2(s * 0.125 * log2(e)) ; folded into Q at proj epilogue
static constexpr float kExpC = 0.125f * 1.44269504f;

// async global->LDS, 16 B per lane. LDS dest must be the wave-uniform base;
// HW adds lane*16. Global src is per-lane.
__device__ __forceinline__ void gl_lds16(const bf16* g, bf16* l) {
  __builtin_amdgcn_global_load_lds(
      (const __attribute__((address_space(1))) unsigned int*)g,
      (__attribute__((address_space(3))) unsigned int*)l, 16, 0, 0);
}

// ---------------- fp32 -> bf16 conversion (x + 4 weights) + RoPE table ----------------
__global__ void cvt_all(const float* __restrict__ x,
                        const float* __restrict__ wq, const float* __restrict__ wk,
                        const float* __restrict__ wv, const float* __restrict__ wo,
                        bf16* __restrict__ xb,
                        bf16* __restrict__ wqb, bf16* __restrict__ wkb,
                        bf16* __restrict__ wvb, bf16* __restrict__ wob,
                        float2* __restrict__ rtab)
{
  const int i = blockIdx.x * 256 + threadIdx.x;   // float4 index
  const int NX4 = (kM * kD) / 4;                  // 1048576
  const int NW4 = (kD * kD) / 4;                  // 262144 = 2^18
  if (i >= NX4 + 4 * NW4) {                       // RoPE cos/sin table: 2048 x 32
    const int idx = i - (NX4 + 4 * NW4);          // exactly 65536 of these
    const int s = idx >> 5, d = idx & 31;
    const float f = exp2f(-(float)d * 0.4152410118609203f);  // 10000^(-d/32)
    float sn, cs;
    sincosf((float)s * f, &sn, &cs);
    rtab[idx] = make_float2(cs, sn);
    return;
  }
  const float* src; bf16* dst; int off;
  if (i < NX4) { src = x; dst = xb; off = i; }
  else {
    const int j = i - NX4;
    const int seg = j >> 18;
    off = j & (NW4 - 1);
    src = (seg == 0) ? wq : (seg == 1) ? wk : (seg == 2) ? wv : wo;
    dst = (seg == 0) ? wqb : (seg == 1) ? wkb : (seg == 2) ? wvb : wob;
  }
  const float4 v = ((const float4*)src)[off];
  bf16x4 o = { (bf16)v.x, (bf16)v.y, (bf16)v.z, (bf16)v.w };
  ((bf16x4*)dst)[off] = o;
}

// ---------------- 128x128 tile bf16 GEMM core, global_load_lds double-buffer --------
// C = A * B^T. A:[M,K], Bw:[N,K], row-major bf16. BK=32, 256 threads, 2x2 waves.
// T3 minimal 2-phase: ONE barrier per K-step; the next tile's 4 async
// global_load_lds are issued right after the barrier and stay in flight under
// the 16 MFMAs (drained by the next barrier's vmcnt(0)).
__device__ __forceinline__ void gemm_core_128(
    const bf16* __restrict__ A, const bf16* __restrict__ Bw,
    int m0, int n0, int K, bf16* smem, f32x4 acc[4][4])
{
  const int t = threadIdx.x, lane = t & 63, wave = t >> 6;
  const int wm = wave >> 1, wn = wave & 1;
  const int srow = lane >> 2;          // 0..15
  const int scol = (lane & 3) * 8;     // 0,8,16,24
  const bf16* ga0 = A  + (size_t)(m0 + wave * 16 + srow) * K + scol;
  const bf16* ga1 = ga0 + (size_t)64 * K;
  const bf16* gb0 = Bw + (size_t)(n0 + wave * 16 + srow) * K + scol;
  const bf16* gb1 = gb0 + (size_t)64 * K;
  const int woff = wave * 512;

  {  // prologue: stage tile k=0 into buf0
    bf16* lb = smem;
    gl_lds16(ga0, lb + woff);
    gl_lds16(ga1, lb + 2048 + woff);
    gl_lds16(gb0, lb + 4096 + woff);
    gl_lds16(gb1, lb + 6144 + woff);
  }
  int cur = 0;
  for (int k0 = 0; k0 < K; k0 += 32) {
    __syncthreads();   // vmcnt(0) drain: buf[cur] staged; prior reads of buf[cur^1] done
    if (k0 + 32 < K) { // issue next tile early; in flight during MFMA below
      bf16* lb = smem + (cur ^ 1) * 8192;
      gl_lds16(ga0 + k0 + 32, lb + woff);
      gl_lds16(ga1 + k0 + 32, lb + 2048 + woff);
      gl_lds16(gb0 + k0 + 32, lb + 4096 + woff);
      gl_lds16(gb1 + k0 + 32, lb + 6144 + woff);
    }
    const bf16* aT = smem + cur * 8192;
    const bf16* bT = aT + 4096;
    bf16x8 af[4], bfr[4];
#pragma unroll
    for (int i = 0; i < 4; ++i) {
      af[i]  = *(const bf16x8*)(aT + (wm * 64 + i * 16 + (lane & 15)) * 32 + (lane >> 4) * 8);
      bfr[i] = *(const bf16x8*)(bT + (wn * 64 + i * 16 + (lane & 15)) * 32 + (lane >> 4) * 8);
    }
#pragma unroll
    for (int i = 0; i < 4; ++i)
#pragma unroll
      for (int j = 0; j < 4; ++j)
        acc[i][j] = MFMA16(af[i], bfr[j], acc[i][j]);
    cur ^= 1;
  }
}

// ---------------- QKV projection + RoPE epilogue; V written pre-transposed ----------------
__global__ __launch_bounds__(256, 4) void proj_qkv(
    const bf16* __restrict__ xb,
    const bf16* __restrict__ wqb, const bf16* __restrict__ wkb, const bf16* __restrict__ wvb,
    bf16* __restrict__ Qb, bf16* __restrict__ Kb, bf16* __restrict__ Vt,
    const float2* __restrict__ rtab)
{
  __shared__ __align__(16) bf16 smem[16384];   // 32 KB: gemm dbuf, then V-transpose
  const int z = blockIdx.z;
  const bf16* Ww = (z == 0) ? wqb : (z == 1) ? wkb : wvb;
  const int m0 = blockIdx.x * 128, n0 = blockIdx.y * 128;
  f32x4 acc[4][4] = {};
  gemm_core_128(xb, Ww, m0, n0, kD, smem, acc);

  const int lane = threadIdx.x & 63, wave = threadIdx.x >> 6;
  const int wm = wave >> 1, wn = wave & 1, quad = lane >> 4, lc = lane & 15;
  const int hh = (n0 >> 6) + wn;     // head index; wave's 64-col span == one head
  if (z == 2) {                      // V: transpose via LDS, store [bh][d][s] coalesced
    __syncthreads();                 // all waves done reading gemm smem
    const int t = threadIdx.x;
    const int row = t >> 1;          // n = head*64 + d, 0..127
    const int coff = (t & 1) * 32;
    const int bidx = m0 >> 11;
    const int hh2 = (n0 >> 6) + (row >> 6);
    const int d = row & 63;
    bf16* vtr = smem;                // [128 n][72] per pass (m-half)
#pragma unroll
    for (int p = 0; p < 2; ++p) {
      if (p) __syncthreads();        // pass-0 reads done before overwrite
      if (wm == p) {                 // waves owning m in [p*64, p*64+64)
#pragma unroll
        for (int i = 0; i < 4; ++i)
#pragma unroll
          for (int j = 0; j < 4; ++j) {
            bf16x4 pk;
#pragma unroll
            for (int r = 0; r < 4; ++r) pk[r] = (bf16)acc[i][j][r];
            *(bf16x4*)&vtr[(wn * 64 + j * 16 + lc) * 72 + i * 16 + quad * 4] = pk;
          }
      }
      __syncthreads();
      bf16* dst = Vt + ((size_t)(bidx * kH + hh2) * kHD + d) * kS
                     + (m0 & 2047) + p * 64 + coff;
#pragma unroll
      for (int u = 0; u < 4; ++u)
        *(uint4*)(dst + u * 8) = *(const uint4*)&vtr[row * 72 + coff + u * 8];
    }
  } else {                           // Q/K: RoPE in-register (pair d with d+32)
    bf16* Op = (z == 0) ? Qb : Kb;
    const float f = (z == 0) ? kExpC : 1.0f;   // fold softmax scale into Q
#pragma unroll
    for (int j = 0; j < 2; ++j) {
      const int d = j * 16 + lc;     // 0..31
#pragma unroll
      for (int i = 0; i < 4; ++i)
#pragma unroll
        for (int r = 0; r < 4; ++r) {
          const int m = m0 + wm * 64 + i * 16 + quad * 4 + r;
          const int bidx = m >> 11, s = m & 2047;
          const float2 cs = rtab[s * 32 + d];
          const float v0 = acc[i][j][r], v1 = acc[i][j + 2][r];
          bf16* dst = Op + ((size_t)(bidx * kH + hh) * kS + s) * kHD;
          dst[d]      = (bf16)((v0 * cs.x - v1 * cs.y) * f);
          dst[d + 32] = (bf16)((v1 * cs.x + v0 * cs.y) * f);
        }
    }
  }
}

// ---------------- flash attention v7: 8-wave blocks for 4 waves/SIMD occupancy ------
// r6 post-mortem: three staging schemes (r1 sync, r5 T14-regs, r6 gl_lds-dbuf) all
// land 49-52 us with MfmaUtil ~28-31 — staging was never the wall. The kernel is
// LATENCY-bound on the serial QK^T->exp2->PV chain with only 2 waves/SIMD.
// Fix: 512-thread blocks (8 waves x 16 q-rows, QBLK=128), grid STAYS 512:
//   2 blocks/CU x 8 waves = 16 waves/CU = 4 waves/SIMD (was 2).
// r3's trap avoided: block count unchanged -> global staging traffic unchanged.
// Cost: LDS-read per compute x2 (~250 GB/s/CU < 270 cap, conflicts <=2-way).
// VGPR trimmed for the 4-wave/SIMD cap (128): 1 tm, sc[4] two-pass, ephemeral kf.
// No cross-barrier registers (r5 lesson). K LDS-staged (r2 lesson).
__global__ __launch_bounds__(512, 4) void attn(
    const bf16* __restrict__ Qb, const bf16* __restrict__ Kb,
    const bf16* __restrict__ Vt, bf16* __restrict__ Ob)
{
  __shared__ __align__(16) bf16 kT2[2][128 * 64];
  __shared__ __align__(16) bf16 vT2[2][64 * 128];
  const int t = threadIdx.x, lane = t & 63, wave = t >> 6;   // wave 0..7
  const int quad = lane >> 4, lc = lane & 15;
  const int bid = blockIdx.x;
  const int qt = (bid >> 3) & 15;
  const int bh = (bid & 7) * 4 + (bid >> 7);     // XCD-locality decode
  const size_t base = (size_t)bh * kS * kHD;
  const bf16* Qp = Qb + base + (size_t)qt * 128 * kHD;
  const bf16* Kp = Kb + base;
  const bf16* Vp = Vt + base;                     // [d][s]

  // Q fragments (B-operand layout); each wave owns 16 q-rows
  bf16x8 qf[2];
#pragma unroll
  for (int ks = 0; ks < 2; ++ks)
    qf[ks] = *(const bf16x8*)(Qp + (wave * 16 + lc) * kHD + ks * 32 + quad * 8);

  f32x4 oacc[4] = {};
  f32x4 lacc = {};
  const bf16 one = (bf16)1.0f;
  const bf16x8 ones = { one, one, one, one, one, one, one, one };

  // staging sources (pre-swizzled per-lane global addresses, rule 21).
  // K [128][64]: wave w, issue i (0,1) covers rows w*16+i*8+(l>>3); data colblk
  //   (l&7)^(row&7), row&7 = l>>3.
  // V [64][128]: wave w, issue i covers rows w*8+i*4+(l>>4); data colblk16
  //   (l&15)^(row&7), row&7 = i*4+(l>>4).
  const bf16* kst  = Kp + (size_t)(wave * 16 + (lane >> 3)) * kHD
                        + 8 * ((lane & 7) ^ (lane >> 3));
  const bf16* vst0 = Vp + (size_t)(wave * 8 + (lane >> 4)) * kS
                        + 8 * ((lane & 15) ^ (lane >> 4));
  const bf16* vst1 = Vp + (size_t)(wave * 8 + 4 + (lane >> 4)) * kS
                        + 8 * ((lane & 15) ^ (4 + (lane >> 4)));
  const int ldsb = wave * 1024;                   // elems; + i*512 per issue

  // prologue: stage tile 0 into buf 0 (2 K-issues + 2 V-issues per wave)
  gl_lds16(kst,            &kT2[0][ldsb]);
  gl_lds16(kst + 8 * kHD,  &kT2[0][ldsb + 512]);
  gl_lds16(vst0,           &vT2[0][ldsb]);
  gl_lds16(vst1,           &vT2[0][ldsb + 512]);

  int cur = 0;
  for (int kt = 0; kt < kS / 128; ++kt) {
    __syncthreads();   // vmcnt(0) drain: buf[cur] staged; prior reads of buf[cur^1] done
    if (kt + 1 < kS / 128) {         // issue kt+1 DMA; in flight under all compute below
      const bf16* kn = kst + (size_t)(kt + 1) * 128 * kHD;
      const int vo = (kt + 1) * 128;
      gl_lds16(kn,            &kT2[cur ^ 1][ldsb]);
      gl_lds16(kn + 8 * kHD,  &kT2[cur ^ 1][ldsb + 512]);
      gl_lds16(vst0 + vo,     &vT2[cur ^ 1][ldsb]);
      gl_lds16(vst1 + vo,     &vT2[cur ^ 1][ldsb + 512]);
    }
    const bf16* kbuf = kT2[cur];
    const bf16* vbuf = vT2[cur];

    // S^T = K Q^T in two halves (sc[4] reused -> VGPR), exp2 straight to A-frags
    bf16x8 pfrag[4];
#pragma unroll
    for (int half = 0; half < 2; ++half) {
      f32x4 sc[4] = {};
#pragma unroll
      for (int nkk = 0; nkk < 4; ++nkk) {
        const int nk = half * 4 + nkk;
        const bf16x8 k0 = *(const bf16x8*)&kbuf[(nk * 16 + lc) * 64
                                                + 8 * ((0 + quad) ^ (lane & 7))];
        const bf16x8 k1 = *(const bf16x8*)&kbuf[(nk * 16 + lc) * 64
                                                + 8 * ((4 + quad) ^ (lane & 7))];
        sc[nkk] = MFMA16(k0, qf[0], sc[nkk]);
        sc[nkk] = MFMA16(k1, qf[1], sc[nkk]);
      }
#pragma unroll
      for (int kpp = 0; kpp < 2; ++kpp) {
        bf16x8 p;
#pragma unroll
        for (int j = 0; j < 4; ++j) {
          p[j]     = (bf16)__builtin_amdgcn_exp2f(sc[2 * kpp][j]);
          p[j + 4] = (bf16)__builtin_amdgcn_exp2f(sc[2 * kpp + 1][j]);
        }
        pfrag[half * 2 + kpp] = p;
      }
    }

    // row sums via ones-MFMA (same remapped key order on both operands)
#pragma unroll
    for (int kp = 0; kp < 4; ++kp)
      lacc = MFMA16(pfrag[kp], ones, lacc);

    // O += P V : V fragment = two b64 swizzled reads matching remapped key order
#pragma unroll
    for (int nd = 0; nd < 4; ++nd)
#pragma unroll
      for (int kp = 0; kp < 4; ++kp) {
        const int r = nd * 16 + lc;
        const bf16x4 lo = *(const bf16x4*)&vbuf[r * 128
            + (((kp * 4 + (quad >> 1)) ^ (lane & 7)) * 8 + (quad & 1) * 4)];
        const bf16x4 hi = *(const bf16x4*)&vbuf[r * 128
            + (((kp * 4 + 2 + (quad >> 1)) ^ (lane & 7)) * 8 + (quad & 1) * 4)];
        const bf16x8 vfr = __builtin_shufflevector(lo, hi, 0, 1, 2, 3, 4, 5, 6, 7);
        oacc[nd] = MFMA16(pfrag[kp], vfr, oacc[nd]);
      }
    cur ^= 1;
  }

  // normalize + store O as bf16 in [B,S,D] layout for the output GEMM
  const int b = bh >> 4, h = bh & 15;
#pragma unroll
  for (int r = 0; r < 4; ++r) {
    const float inv = 1.0f / lacc[r];
    const int s = qt * 128 + wave * 16 + quad * 4 + r;
    bf16* dst = Ob + ((size_t)(b * kS + s)) * kD + h * kHD;
#pragma unroll
    for (int nd = 0; nd < 4; ++nd)
      dst[nd * 16 + lc] = (bf16)(oacc[nd][r] * inv);
  }
}

// ---------------- output projection (fp32 epilogue) ----------------
__global__ __launch_bounds__(256, 4) void out_proj(
    const bf16* __restrict__ Ab, const bf16* __restrict__ wob, float* __restrict__ Cout)
{
  __shared__ __align__(16) bf16 smem[16384];   // 32 KB gemm dbuf
  const int m0 = blockIdx.x * 128, n0 = blockIdx.y * 128;
  f32x4 acc[4][4] = {};
  gemm_core_128(Ab, wob, m0, n0, kD, smem, acc);
  const int lane = threadIdx.x & 63, wave = threadIdx.x >> 6;
  const int wm = wave >> 1, wn = wave & 1, quad = lane >> 4, lc = lane & 15;
#pragma unroll
  for (int i = 0; i < 4; ++i)
#pragma unroll
    for (int r = 0; r < 4; ++r) {
      const int m = m0 + wm * 64 + i * 16 + quad * 4 + r;
#pragma unroll
      for (int j = 0; j < 4; ++j)
        Cout[(size_t)m * kD + n0 + wn * 64 + j * 16 + lc] = acc[i][j][r];
    }
}

extern "C" void kernel_launch(void* const* d_in, const int* in_sizes, int n_in,
                              void* d_out, int out_size, void* d_ws, size_t ws_size,
                              hipStream_t stream)
{
  const float* x  = (const float*)d_in[0];
  const float* wq = (const float*)d_in[1];
  const float* wk = (const float*)d_in[2];
  const float* wv = (const float*)d_in[3];
  const float* wo = (const float*)d_in[4];
  float* out = (float*)d_out;

  char* ws = (char*)d_ws;
  const size_t MB = 1024 * 1024;
  if (ws_size < 57 * MB) return;
  bf16* xb  = (bf16*)(ws + 0 * MB);   // 8 MB
  bf16* wqb = (bf16*)(ws + 8 * MB);   // 2 MB each
  bf16* wkb = (bf16*)(ws + 10 * MB);
  bf16* wvb = (bf16*)(ws + 12 * MB);
  bf16* wob = (bf16*)(ws + 14 * MB);
  bf16* Qb  = (bf16*)(ws + 16 * MB);  // 8 MB each, [B*H][S][64]
  bf16* Kb  = (bf16*)(ws + 24 * MB);
  bf16* Ob  = (bf16*)(ws + 40 * MB);  // 8 MB, [B,S,D]
  float2* rtab = (float2*)(ws + 48 * MB);  // 512 KB RoPE table
  bf16* Vtp = (bf16*)(ws + 49 * MB);  // 8 MB, V transposed [B*H][64][S]

  cvt_all<<<8448, 256, 0, stream>>>(x, wq, wk, wv, wo, xb, wqb, wkb, wvb, wob, rtab);
  proj_qkv<<<dim3(32, 8, 3), 256, 0, stream>>>(xb, wqb, wkb, wvb, Qb, Kb, Vtp, rtab);
  attn<<<dim3(512), 512, 0, stream>>>(Qb, Kb, Vtp, Ob);
  out_proj<<<dim3(32, 8), 256, 0, stream>>>(Ob, wob, out);
}

// Round 8
// 178.126 us; speedup vs baseline: 1.2844x; 1.0188x over previous
//
#include <hip/hip_runtime.h>
#include <hip/hip_bf16.h>
#include <math.h>
#include <stdint.h>

typedef __bf16 bf16;
typedef __bf16 bf16x8 __attribute__((ext_vector_type(8)));
typedef __bf16 bf16x4 __attribute__((ext_vector_type(4)));
typedef float  f32x4  __attribute__((ext_vector_type(4)));
typedef float  f32x16 __attribute__((ext_vector_type(16)));
typedef unsigned int u32x4 __attribute__((ext_vector_type(4)));

#define MFMA16(a,b,c) __builtin_amdgcn_mfma_f32_16x16x32_bf16((a),(b),(c),0,0,0)
#define MFMA32(a,b,c) __builtin_amdgcn_mfma_f32_32x32x16_bf16((a),(b),(c),0,0,0)

static constexpr int kB  = 2;
static constexpr int kS  = 2048;
static constexpr int kD  = 1024;
static constexpr int kH  = 16;
static constexpr int kHD = 64;
static constexpr int kM  = kB * kS;         // 4096
// exp(s*0.125) = exp2(s * 0.125 * log2(e)) ; folded into Q at proj epilogue
static constexpr float kExpC = 0.125f * 1.44269504f;

// async global->LDS, 16 B per lane. LDS dest must be the wave-uniform base;
// HW adds lane*16. Global src is per-lane.
__device__ __forceinline__ void gl_lds16(const bf16* g, bf16* l) {
  __builtin_amdgcn_global_load_lds(
      (const __attribute__((address_space(1))) unsigned int*)g,
      (__attribute__((address_space(3))) unsigned int*)l, 16, 0, 0);
}

// pack two f32 -> one u32 of 2 bf16 (no builtin on gfx950 — m240)
__device__ __forceinline__ unsigned cvt_pk_bf16(float lo, float hi) {
  unsigned r;
  asm("v_cvt_pk_bf16_f32 %0, %1, %2" : "=v"(r) : "v"(lo), "v"(hi));
  return r;
}

// ---------------- fp32 -> bf16 conversion (x + 4 weights) + RoPE table ----------------
__global__ void cvt_all(const float* __restrict__ x,
                        const float* __restrict__ wq, const float* __restrict__ wk,
                        const float* __restrict__ wv, const float* __restrict__ wo,
                        bf16* __restrict__ xb,
                        bf16* __restrict__ wqb, bf16* __restrict__ wkb,
                        bf16* __restrict__ wvb, bf16* __restrict__ wob,
                        float2* __restrict__ rtab)
{
  const int i = blockIdx.x * 256 + threadIdx.x;   // float4 index
  const int NX4 = (kM * kD) / 4;                  // 1048576
  const int NW4 = (kD * kD) / 4;                  // 262144 = 2^18
  if (i >= NX4 + 4 * NW4) {                       // RoPE cos/sin table: 2048 x 32
    const int idx = i - (NX4 + 4 * NW4);          // exactly 65536 of these
    const int s = idx >> 5, d = idx & 31;
    const float f = exp2f(-(float)d * 0.4152410118609203f);  // 10000^(-d/32)
    float sn, cs;
    sincosf((float)s * f, &sn, &cs);
    rtab[idx] = make_float2(cs, sn);
    return;
  }
  const float* src; bf16* dst; int off;
  if (i < NX4) { src = x; dst = xb; off = i; }
  else {
    const int j = i - NX4;
    const int seg = j >> 18;
    off = j & (NW4 - 1);
    src = (seg == 0) ? wq : (seg == 1) ? wk : (seg == 2) ? wv : wo;
    dst = (seg == 0) ? wqb : (seg == 1) ? wkb : (seg == 2) ? wvb : wob;
  }
  const float4 v = ((const float4*)src)[off];
  bf16x4 o = { (bf16)v.x, (bf16)v.y, (bf16)v.z, (bf16)v.w };
  ((bf16x4*)dst)[off] = o;
}

// ---------------- 128x128 tile bf16 GEMM core, global_load_lds double-buffer --------
// C = A * B^T. A:[M,K], Bw:[N,K], row-major bf16. BK=32, 256 threads, 2x2 waves.
// T3 minimal 2-phase: ONE barrier per K-step; the next tile's 4 async
// global_load_lds are issued right after the barrier and stay in flight under
// the 16 MFMAs (drained by the next barrier's vmcnt(0)).
__device__ __forceinline__ void gemm_core_128(
    const bf16* __restrict__ A, const bf16* __restrict__ Bw,
    int m0, int n0, int K, bf16* smem, f32x4 acc[4][4])
{
  const int t = threadIdx.x, lane = t & 63, wave = t >> 6;
  const int wm = wave >> 1, wn = wave & 1;
  const int srow = lane >> 2;          // 0..15
  const int scol = (lane & 3) * 8;     // 0,8,16,24
  const bf16* ga0 = A  + (size_t)(m0 + wave * 16 + srow) * K + scol;
  const bf16* ga1 = ga0 + (size_t)64 * K;
  const bf16* gb0 = Bw + (size_t)(n0 + wave * 16 + srow) * K + scol;
  const bf16* gb1 = gb0 + (size_t)64 * K;
  const int woff = wave * 512;

  {  // prologue: stage tile k=0 into buf0
    bf16* lb = smem;
    gl_lds16(ga0, lb + woff);
    gl_lds16(ga1, lb + 2048 + woff);
    gl_lds16(gb0, lb + 4096 + woff);
    gl_lds16(gb1, lb + 6144 + woff);
  }
  int cur = 0;
  for (int k0 = 0; k0 < K; k0 += 32) {
    __syncthreads();   // vmcnt(0) drain: buf[cur] staged; prior reads of buf[cur^1] done
    if (k0 + 32 < K) { // issue next tile early; in flight during MFMA below
      bf16* lb = smem + (cur ^ 1) * 8192;
      gl_lds16(ga0 + k0 + 32, lb + woff);
      gl_lds16(ga1 + k0 + 32, lb + 2048 + woff);
      gl_lds16(gb0 + k0 + 32, lb + 4096 + woff);
      gl_lds16(gb1 + k0 + 32, lb + 6144 + woff);
    }
    const bf16* aT = smem + cur * 8192;
    const bf16* bT = aT + 4096;
    bf16x8 af[4], bfr[4];
#pragma unroll
    for (int i = 0; i < 4; ++i) {
      af[i]  = *(const bf16x8*)(aT + (wm * 64 + i * 16 + (lane & 15)) * 32 + (lane >> 4) * 8);
      bfr[i] = *(const bf16x8*)(bT + (wn * 64 + i * 16 + (lane & 15)) * 32 + (lane >> 4) * 8);
    }
#pragma unroll
    for (int i = 0; i < 4; ++i)
#pragma unroll
      for (int j = 0; j < 4; ++j)
        acc[i][j] = MFMA16(af[i], bfr[j], acc[i][j]);
    cur ^= 1;
  }
}

// ---------------- QKV projection + RoPE epilogue; V written pre-transposed ----------------
__global__ __launch_bounds__(256, 4) void proj_qkv(
    const bf16* __restrict__ xb,
    const bf16* __restrict__ wqb, const bf16* __restrict__ wkb, const bf16* __restrict__ wvb,
    bf16* __restrict__ Qb, bf16* __restrict__ Kb, bf16* __restrict__ Vt,
    const float2* __restrict__ rtab)
{
  __shared__ __align__(16) bf16 smem[16384];   // 32 KB: gemm dbuf, then V-transpose
  const int z = blockIdx.z;
  const bf16* Ww = (z == 0) ? wqb : (z == 1) ? wkb : wvb;
  const int m0 = blockIdx.x * 128, n0 = blockIdx.y * 128;
  f32x4 acc[4][4] = {};
  gemm_core_128(xb, Ww, m0, n0, kD, smem, acc);

  const int lane = threadIdx.x & 63, wave = threadIdx.x >> 6;
  const int wm = wave >> 1, wn = wave & 1, quad = lane >> 4, lc = lane & 15;
  const int hh = (n0 >> 6) + wn;     // head index; wave's 64-col span == one head
  if (z == 2) {                      // V: transpose via LDS, store [bh][d][s] coalesced
    __syncthreads();                 // all waves done reading gemm smem
    const int t = threadIdx.x;
    const int row = t >> 1;          // n = head*64 + d, 0..127
    const int coff = (t & 1) * 32;
    const int bidx = m0 >> 11;
    const int hh2 = (n0 >> 6) + (row >> 6);
    const int d = row & 63;
    bf16* vtr = smem;                // [128 n][72] per pass (m-half)
#pragma unroll
    for (int p = 0; p < 2; ++p) {
      if (p) __syncthreads();        // pass-0 reads done before overwrite
      if (wm == p) {                 // waves owning m in [p*64, p*64+64)
#pragma unroll
        for (int i = 0; i < 4; ++i)
#pragma unroll
          for (int j = 0; j < 4; ++j) {
            bf16x4 pk;
#pragma unroll
            for (int r = 0; r < 4; ++r) pk[r] = (bf16)acc[i][j][r];
            *(bf16x4*)&vtr[(wn * 64 + j * 16 + lc) * 72 + i * 16 + quad * 4] = pk;
          }
      }
      __syncthreads();
      bf16* dst = Vt + ((size_t)(bidx * kH + hh2) * kHD + d) * kS
                     + (m0 & 2047) + p * 64 + coff;
#pragma unroll
      for (int u = 0; u < 4; ++u)
        *(uint4*)(dst + u * 8) = *(const uint4*)&vtr[row * 72 + coff + u * 8];
    }
  } else {                           // Q/K: RoPE in-register (pair d with d+32)
    bf16* Op = (z == 0) ? Qb : Kb;
    const float f = (z == 0) ? kExpC : 1.0f;   // fold softmax scale into Q
#pragma unroll
    for (int j = 0; j < 2; ++j) {
      const int d = j * 16 + lc;     // 0..31
#pragma unroll
      for (int i = 0; i < 4; ++i)
#pragma unroll
        for (int r = 0; r < 4; ++r) {
          const int m = m0 + wm * 64 + i * 16 + quad * 4 + r;
          const int bidx = m >> 11, s = m & 2047;
          const float2 cs = rtab[s * 32 + d];
          const float v0 = acc[i][j][r], v1 = acc[i][j + 2][r];
          bf16* dst = Op + ((size_t)(bidx * kH + hh) * kS + s) * kHD;
          dst[d]      = (bf16)((v0 * cs.x - v1 * cs.y) * f);
          dst[d + 32] = (bf16)((v1 * cs.x + v0 * cs.y) * f);
        }
    }
  }
}

// ---------------- flash attention v8: 32x32x16 MFMA + T12 cvt_pk/permlane pack ------
// r2-r7 lessons: traffic-neutral changes only; no cross-barrier VGPR staging; r1's
// 4-wave/32q/grid-512 shape is the traffic-balanced one. The 49-58 us plateau is
// STRUCTURAL: too many instructions per flop. This round halves operand
// bytes/flop by moving QK^T and PV to mfma_32x32x16:
//   per tile per wave: 32 MFMA32 (vs 72 MFMA16), 16 b128 V-reads (vs 64 b64),
//   rowsum via f32 VALU tree on in-register P (ones-MFMA eliminated).
// P-fragment repack across lane-halves (S^T D-regs: row=(r&3)+8*(r>>2)+4*hi,
// col=q=lane&31 [m74/m101]) is the guide's T12: 4 cvt_pk + 2 permlane32_swap
// per 16-key slice; swap semantics S1 (new_a={a.lo,b.lo}, new_b={a.hi,b.hi})
// makes each swap yield TWO usable B-operand words (w0/w2, w1/w3).
// Staging: r6's gl_lds dbuf + rule-21 XOR swizzles, verbatim (HW-validated).
// O is produced transposed (O^T[d][q]); epilogue transposes via the dead kT
// buffer (stride 72, b64 writes / b128 reads) for coalesced global stores.
__global__ __launch_bounds__(256, 2) void attn(
    const bf16* __restrict__ Qb, const bf16* __restrict__ Kb,
    const bf16* __restrict__ Vt, bf16* __restrict__ Ob)
{
  __shared__ __align__(16) bf16 kT2[2][128 * 64];
  __shared__ __align__(16) bf16 vT2[2][64 * 128];
  const int t = threadIdx.x, lane = t & 63, wave = t >> 6;
  const int l31 = lane & 31, hi = lane >> 5;
  const int bid = blockIdx.x;
  const int qt = (bid >> 3) & 15;
  const int bh = (bid & 7) * 4 + (bid >> 7);     // XCD-locality decode
  const size_t base = (size_t)bh * kS * kHD;
  const bf16* Qp = Qb + base + (size_t)qt * 128 * kHD;
  const bf16* Kp = Kb + base;
  const bf16* Vp = Vt + base;                     // [d][s]

  // Q fragments: B-operand of 32x32x16 (col=q=lane&31, k=hi*8+j, d-slice ks)
  bf16x8 qf[4];
#pragma unroll
  for (int ks = 0; ks < 4; ++ks)
    qf[ks] = *(const bf16x8*)(Qp + (size_t)(wave * 32 + l31) * kHD + ks * 16 + hi * 8);

  f32x16 oacc[2] = {};   // O^T: row=d=(r&3)+8*(r>>2)+4*hi (+nb*32), col=q=lane&31
  float lsum = 0.f;

  // staging sources (pre-swizzled per-lane global addresses, rule 21; r6-verbatim)
  const bf16* kst  = Kp + (size_t)(wave * 32 + (lane >> 3)) * kHD
                        + 8 * ((lane & 7) ^ (lane >> 3));
  const bf16* vst0 = Vp + (size_t)(wave * 16 + (lane >> 4)) * kS
                        + 8 * ((lane & 15) ^ (lane >> 4));
  const bf16* vst1 = Vp + (size_t)(wave * 16 + (lane >> 4)) * kS
                        + 8 * (((lane & 15) ^ (lane >> 4)) ^ 4);
  const int ldsb = wave * 2048;                   // elems; + i*512 per issue

  // prologue: stage tile 0 into buf 0 (4 K-issues + 4 V-issues per wave)
#pragma unroll
  for (int i = 0; i < 4; ++i) {
    gl_lds16(kst + (size_t)i * 8 * kHD, &kT2[0][ldsb + i * 512]);
    gl_lds16(((i & 1) ? vst1 : vst0) + (size_t)i * 4 * kS, &vT2[0][ldsb + i * 512]);
  }

  int cur = 0;
  const int NT = kS / 128;
  for (int kt = 0; kt < NT; ++kt) {
    __syncthreads();   // vmcnt(0) drain: buf[cur] staged; prior reads of buf[cur^1] done
    if (kt + 1 < NT) {               // issue kt+1 DMA; in flight under all compute below
      const bf16* kn = kst + (size_t)(kt + 1) * 128 * kHD;
      const int vo = (kt + 1) * 128;
#pragma unroll
      for (int i = 0; i < 4; ++i) {
        gl_lds16(kn + (size_t)i * 8 * kHD, &kT2[cur ^ 1][ldsb + i * 512]);
        gl_lds16(((i & 1) ? vst1 : vst0) + (size_t)i * 4 * kS + vo,
                 &vT2[cur ^ 1][ldsb + i * 512]);
      }
    }
    const bf16* kbuf = kT2[cur];
    const bf16* vbuf = vT2[cur];

    // S^T[key][q] = K Q^T : 4 key-blocks x 4 d-slices of 32x32x16
    f32x16 sacc[4] = {};
#pragma unroll
    for (int knb = 0; knb < 4; ++knb)
#pragma unroll
      for (int ks = 0; ks < 4; ++ks) {
        const bf16x8 kf = *(const bf16x8*)&kbuf[(knb * 32 + l31) * 64
                                               + 8 * ((ks * 2 + hi) ^ (lane & 7))];
        sacc[knb] = MFMA32(kf, qf[ks], sacc[knb]);
      }

    // p = exp2(s); rowsum on VALU; pack to PV B-fragments (T12)
    bf16x8 pfrag[8];
#pragma unroll
    for (int knb = 0; knb < 4; ++knb) {
      float pe[16];
#pragma unroll
      for (int r = 0; r < 16; ++r) pe[r] = __builtin_amdgcn_exp2f(sacc[knb][r]);
      lsum += (((pe[0] + pe[1]) + (pe[2] + pe[3])) + ((pe[4] + pe[5]) + (pe[6] + pe[7])))
            + (((pe[8] + pe[9]) + (pe[10] + pe[11])) + ((pe[12] + pe[13]) + (pe[14] + pe[15])));
#pragma unroll
      for (int h2 = 0; h2 < 2; ++h2) {
        unsigned a0 = cvt_pk_bf16(pe[8 * h2 + 0], pe[8 * h2 + 1]);
        unsigned a1 = cvt_pk_bf16(pe[8 * h2 + 2], pe[8 * h2 + 3]);
        unsigned b0 = cvt_pk_bf16(pe[8 * h2 + 4], pe[8 * h2 + 5]);
        unsigned b1 = cvt_pk_bf16(pe[8 * h2 + 6], pe[8 * h2 + 7]);
        asm("v_permlane32_swap_b32 %0, %1" : "+v"(a0), "+v"(b0));
        asm("v_permlane32_swap_b32 %0, %1" : "+v"(a1), "+v"(b1));
        u32x4 w; w.x = a0; w.y = a1; w.z = b0; w.w = b1;   // words w0,w1,w2,w3
        pfrag[knb * 2 + h2] = __builtin_bit_cast(bf16x8, w);
      }
    }

    // O^T += V^T P : A = V^T slice (row=d, k=key), B = P slice (k=key, col=q)
#pragma unroll
    for (int nb = 0; nb < 2; ++nb)
#pragma unroll
      for (int tt = 0; tt < 8; ++tt) {
        const bf16x8 vf = *(const bf16x8*)&vbuf[(nb * 32 + l31) * 128
                                               + 8 * ((tt * 2 + hi) ^ (lane & 7))];
        oacc[nb] = MFMA32(vf, pfrag[tt], oacc[nb]);
      }
    cur ^= 1;
  }

  // epilogue: finalize rowsum across lane-halves, normalize, LDS-transpose, store
  __syncthreads();                 // all waves done reading K/V tiles; reuse kT2
  const float total = lsum + __shfl_xor(lsum, 32);
  const float inv = 1.0f / total;
  bf16* tb = &kT2[0][0] + wave * 2304;            // per-wave [32 q][stride 72]
#pragma unroll
  for (int nb = 0; nb < 2; ++nb)
#pragma unroll
    for (int rq = 0; rq < 4; ++rq) {
      bf16x4 p4;
#pragma unroll
      for (int e = 0; e < 4; ++e) p4[e] = (bf16)(oacc[nb][rq * 4 + e] * inv);
      *(bf16x4*)&tb[l31 * 72 + nb * 32 + rq * 8 + hi * 4] = p4;
    }
  asm volatile("s_waitcnt lgkmcnt(0)" ::: "memory");
  const int b = bh >> 4, h = bh & 15;
  const int q = lane >> 1, hf = lane & 1;
  const bf16* srcl = &tb[q * 72 + hf * 32];
  bf16* dst = Ob + ((size_t)(b * kS + qt * 128 + wave * 32 + q)) * kD + h * kHD + hf * 32;
#pragma unroll
  for (int u = 0; u < 4; ++u)
    *(uint4*)(dst + u * 8) = *(const uint4*)(srcl + u * 8);
}

// ---------------- output projection (fp32 epilogue) ----------------
__global__ __launch_bounds__(256, 4) void out_proj(
    const bf16* __restrict__ Ab, const bf16* __restrict__ wob, float* __restrict__ Cout)
{
  __shared__ __align__(16) bf16 smem[16384];   // 32 KB gemm dbuf
  const int m0 = blockIdx.x * 128, n0 = blockIdx.y * 128;
  f32x4 acc[4][4] = {};
  gemm_core_128(Ab, wob, m0, n0, kD, smem, acc);
  const int lane = threadIdx.x & 63, wave = threadIdx.x >> 6;
  const int wm = wave >> 1, wn = wave & 1, quad = lane >> 4, lc = lane & 15;
#pragma unroll
  for (int i = 0; i < 4; ++i)
#pragma unroll
    for (int r = 0; r < 4; ++r) {
      const int m = m0 + wm * 64 + i * 16 + quad * 4 + r;
#pragma unroll
      for (int j = 0; j < 4; ++j)
        Cout[(size_t)m * kD + n0 + wn * 64 + j * 16 + lc] = acc[i][j][r];
    }
}

extern "C" void kernel_launch(void* const* d_in, const int* in_sizes, int n_in,
                              void* d_out, int out_size, void* d_ws, size_t ws_size,
                              hipStream_t stream)
{
  const float* x  = (const float*)d_in[0];
  const float* wq = (const float*)d_in[1];
  const float* wk = (const float*)d_in[2];
  const float* wv = (const float*)d_in[3];
  const float* wo = (const float*)d_in[4];
  float* out = (float*)d_out;

  char* ws = (char*)d_ws;
  const size_t MB = 1024 * 1024;
  if (ws_size < 57 * MB) return;
  bf16* xb  = (bf16*)(ws + 0 * MB);   // 8 MB
  bf16* wqb = (bf16*)(ws + 8 * MB);   // 2 MB each
  bf16* wkb = (bf16*)(ws + 10 * MB);
  bf16* wvb = (bf16*)(ws + 12 * MB);
  bf16* wob = (bf16*)(ws + 14 * MB);
  bf16* Qb  = (bf16*)(ws + 16 * MB);  // 8 MB each, [B*H][S][64]
  bf16* Kb  = (bf16*)(ws + 24 * MB);
  bf16* Ob  = (bf16*)(ws + 40 * MB);  // 8 MB, [B,S,D]
  float2* rtab = (float2*)(ws + 48 * MB);  // 512 KB RoPE table
  bf16* Vtp = (bf16*)(ws + 49 * MB);  // 8 MB, V transposed [B*H][64][S]

  cvt_all<<<8448, 256, 0, stream>>>(x, wq, wk, wv, wo, xb, wqb, wkb, wvb, wob, rtab);
  proj_qkv<<<dim3(32, 8, 3), 256, 0, stream>>>(xb, wqb, wkb, wvb, Qb, Kb, Vtp, rtab);
  attn<<<dim3(512), 256, 0, stream>>>(Qb, Kb, Vtp, Ob);
  out_proj<<<dim3(32, 8), 256, 0, stream>>>(Ob, wob, out);
}

// Round 9
// 173.891 us; speedup vs baseline: 1.3157x; 1.0244x over previous
//
#include <hip/hip_runtime.h>
#include <hip/hip_bf16.h>
#include <math.h>
#include <stdint.h>

typedef __bf16 bf16;
typedef __bf16 bf16x8 __attribute__((ext_vector_type(8)));
typedef __bf16 bf16x4 __attribute__((ext_vector_type(4)));
typedef float  f32x4  __attribute__((ext_vector_type(4)));
typedef float  f32x16 __attribute__((ext_vector_type(16)));
typedef unsigned int u32x4 __attribute__((ext_vector_type(4)));

#define MFMA16(a,b,c) __builtin_amdgcn_mfma_f32_16x16x32_bf16((a),(b),(c),0,0,0)
#define MFMA32(a,b,c) __builtin_amdgcn_mfma_f32_32x32x16_bf16((a),(b),(c),0,0,0)

static constexpr int kB  = 2;
static constexpr int kS  = 2048;
static constexpr int kD  = 1024;
static constexpr int kH  = 16;
static constexpr int kHD = 64;
static constexpr int kM  = kB * kS;         // 4096
// exp(s*0.125) = exp2(s * 0.125 * log2(e)) ; folded into Q at proj epilogue
static constexpr float kExpC = 0.125f * 1.44269504f;

// async global->LDS, 16 B per lane. LDS dest must be the wave-uniform base;
// HW adds lane*16. Global src is per-lane.
__device__ __forceinline__ void gl_lds16(const bf16* g, bf16* l) {
  __builtin_amdgcn_global_load_lds(
      (const __attribute__((address_space(1))) unsigned int*)g,
      (__attribute__((address_space(3))) unsigned int*)l, 16, 0, 0);
}

// pack two f32 -> one u32 of 2 bf16 (no builtin on gfx950 — m240)
__device__ __forceinline__ unsigned cvt_pk_bf16(float lo, float hi) {
  unsigned r;
  asm("v_cvt_pk_bf16_f32 %0, %1, %2" : "=v"(r) : "v"(lo), "v"(hi));
  return r;
}

// ---------------- fp32 -> bf16 conversion (x + 4 weights) + RoPE table ----------------
__global__ void cvt_all(const float* __restrict__ x,
                        const float* __restrict__ wq, const float* __restrict__ wk,
                        const float* __restrict__ wv, const float* __restrict__ wo,
                        bf16* __restrict__ xb,
                        bf16* __restrict__ wqb, bf16* __restrict__ wkb,
                        bf16* __restrict__ wvb, bf16* __restrict__ wob,
                        float2* __restrict__ rtab)
{
  const int i = blockIdx.x * 256 + threadIdx.x;   // float4 index
  const int NX4 = (kM * kD) / 4;                  // 1048576
  const int NW4 = (kD * kD) / 4;                  // 262144 = 2^18
  if (i >= NX4 + 4 * NW4) {                       // RoPE cos/sin table: 2048 x 32
    const int idx = i - (NX4 + 4 * NW4);          // exactly 65536 of these
    const int s = idx >> 5, d = idx & 31;
    const float f = exp2f(-(float)d * 0.4152410118609203f);  // 10000^(-d/32)
    float sn, cs;
    sincosf((float)s * f, &sn, &cs);
    rtab[idx] = make_float2(cs, sn);
    return;
  }
  const float* src; bf16* dst; int off;
  if (i < NX4) { src = x; dst = xb; off = i; }
  else {
    const int j = i - NX4;
    const int seg = j >> 18;
    off = j & (NW4 - 1);
    src = (seg == 0) ? wq : (seg == 1) ? wk : (seg == 2) ? wv : wo;
    dst = (seg == 0) ? wqb : (seg == 1) ? wkb : (seg == 2) ? wvb : wob;
  }
  const float4 v = ((const float4*)src)[off];
  bf16x4 o = { (bf16)v.x, (bf16)v.y, (bf16)v.z, (bf16)v.w };
  ((bf16x4*)dst)[off] = o;
}

// ---------------- 128x128 tile bf16 GEMM core, global_load_lds double-buffer --------
// C = A * B^T. A:[M,K], Bw:[N,K], row-major bf16. BK=32, 256 threads, 2x2 waves.
// T3 minimal 2-phase: ONE barrier per K-step; the next tile's 4 async
// global_load_lds are issued right after the barrier and stay in flight under
// the 16 MFMAs (drained by the next barrier's vmcnt(0)).
__device__ __forceinline__ void gemm_core_128(
    const bf16* __restrict__ A, const bf16* __restrict__ Bw,
    int m0, int n0, int K, bf16* smem, f32x4 acc[4][4])
{
  const int t = threadIdx.x, lane = t & 63, wave = t >> 6;
  const int wm = wave >> 1, wn = wave & 1;
  const int srow = lane >> 2;          // 0..15
  const int scol = (lane & 3) * 8;     // 0,8,16,24
  const bf16* ga0 = A  + (size_t)(m0 + wave * 16 + srow) * K + scol;
  const bf16* ga1 = ga0 + (size_t)64 * K;
  const bf16* gb0 = Bw + (size_t)(n0 + wave * 16 + srow) * K + scol;
  const bf16* gb1 = gb0 + (size_t)64 * K;
  const int woff = wave * 512;

  {  // prologue: stage tile k=0 into buf0
    bf16* lb = smem;
    gl_lds16(ga0, lb + woff);
    gl_lds16(ga1, lb + 2048 + woff);
    gl_lds16(gb0, lb + 4096 + woff);
    gl_lds16(gb1, lb + 6144 + woff);
  }
  int cur = 0;
  for (int k0 = 0; k0 < K; k0 += 32) {
    __syncthreads();   // vmcnt(0) drain: buf[cur] staged; prior reads of buf[cur^1] done
    if (k0 + 32 < K) { // issue next tile early; in flight during MFMA below
      bf16* lb = smem + (cur ^ 1) * 8192;
      gl_lds16(ga0 + k0 + 32, lb + woff);
      gl_lds16(ga1 + k0 + 32, lb + 2048 + woff);
      gl_lds16(gb0 + k0 + 32, lb + 4096 + woff);
      gl_lds16(gb1 + k0 + 32, lb + 6144 + woff);
    }
    const bf16* aT = smem + cur * 8192;
    const bf16* bT = aT + 4096;
    bf16x8 af[4], bfr[4];
#pragma unroll
    for (int i = 0; i < 4; ++i) {
      af[i]  = *(const bf16x8*)(aT + (wm * 64 + i * 16 + (lane & 15)) * 32 + (lane >> 4) * 8);
      bfr[i] = *(const bf16x8*)(bT + (wn * 64 + i * 16 + (lane & 15)) * 32 + (lane >> 4) * 8);
    }
#pragma unroll
    for (int i = 0; i < 4; ++i)
#pragma unroll
      for (int j = 0; j < 4; ++j)
        acc[i][j] = MFMA16(af[i], bfr[j], acc[i][j]);
    cur ^= 1;
  }
}

// ---------------- QKV projection + RoPE epilogue; V written pre-transposed ----------------
__global__ __launch_bounds__(256, 4) void proj_qkv(
    const bf16* __restrict__ xb,
    const bf16* __restrict__ wqb, const bf16* __restrict__ wkb, const bf16* __restrict__ wvb,
    bf16* __restrict__ Qb, bf16* __restrict__ Kb, bf16* __restrict__ Vt,
    const float2* __restrict__ rtab)
{
  __shared__ __align__(16) bf16 smem[16384];   // 32 KB: gemm dbuf, then V-transpose
  const int z = blockIdx.z;
  const bf16* Ww = (z == 0) ? wqb : (z == 1) ? wkb : wvb;
  const int m0 = blockIdx.x * 128, n0 = blockIdx.y * 128;
  f32x4 acc[4][4] = {};
  gemm_core_128(xb, Ww, m0, n0, kD, smem, acc);

  const int lane = threadIdx.x & 63, wave = threadIdx.x >> 6;
  const int wm = wave >> 1, wn = wave & 1, quad = lane >> 4, lc = lane & 15;
  const int hh = (n0 >> 6) + wn;     // head index; wave's 64-col span == one head
  if (z == 2) {                      // V: transpose via LDS, store [bh][d][s] coalesced
    __syncthreads();                 // all waves done reading gemm smem
    const int t = threadIdx.x;
    const int row = t >> 1;          // n = head*64 + d, 0..127
    const int coff = (t & 1) * 32;
    const int bidx = m0 >> 11;
    const int hh2 = (n0 >> 6) + (row >> 6);
    const int d = row & 63;
    bf16* vtr = smem;                // [128 n][72] per pass (m-half)
#pragma unroll
    for (int p = 0; p < 2; ++p) {
      if (p) __syncthreads();        // pass-0 reads done before overwrite
      if (wm == p) {                 // waves owning m in [p*64, p*64+64)
#pragma unroll
        for (int i = 0; i < 4; ++i)
#pragma unroll
          for (int j = 0; j < 4; ++j) {
            bf16x4 pk;
#pragma unroll
            for (int r = 0; r < 4; ++r) pk[r] = (bf16)acc[i][j][r];
            *(bf16x4*)&vtr[(wn * 64 + j * 16 + lc) * 72 + i * 16 + quad * 4] = pk;
          }
      }
      __syncthreads();
      bf16* dst = Vt + ((size_t)(bidx * kH + hh2) * kHD + d) * kS
                     + (m0 & 2047) + p * 64 + coff;
#pragma unroll
      for (int u = 0; u < 4; ++u)
        *(uint4*)(dst + u * 8) = *(const uint4*)&vtr[row * 72 + coff + u * 8];
    }
  } else {                           // Q/K: RoPE in-register (pair d with d+32)
    bf16* Op = (z == 0) ? Qb : Kb;
    const float f = (z == 0) ? kExpC : 1.0f;   // fold softmax scale into Q
#pragma unroll
    for (int j = 0; j < 2; ++j) {
      const int d = j * 16 + lc;     // 0..31
#pragma unroll
      for (int i = 0; i < 4; ++i)
#pragma unroll
        for (int r = 0; r < 4; ++r) {
          const int m = m0 + wm * 64 + i * 16 + quad * 4 + r;
          const int bidx = m >> 11, s = m & 2047;
          const float2 cs = rtab[s * 32 + d];
          const float v0 = acc[i][j][r], v1 = acc[i][j + 2][r];
          bf16* dst = Op + ((size_t)(bidx * kH + hh) * kS + s) * kHD;
          dst[d]      = (bf16)((v0 * cs.x - v1 * cs.y) * f);
          dst[d + 32] = (bf16)((v1 * cs.x + v0 * cs.y) * f);
        }
    }
  }
}

// ---------------- flash attention v9: key-split 8-wave blocks (4 waves/SIMD) --------
// r8 post-mortem: 32x32+T12 restructure WON (49.2->45.7) but occupancy is pinned
// at 2 waves/SIMD (grid 512 x 4 waves); pipes idle between dependent phases.
// All prior occupancy attempts broke the traffic invariant (r3: staging x2;
// r7: LDS-read x2). Key-split does not: 8 waves, wave w owns q-group (w&3, 32
// rows) x key-half (w>>2, 64 of 128 keys). Per-block global staging, LDS-read
// bytes, and MFMA count are ALL unchanged; only a one-time ~37 KB cross-wave
// O/lsum LDS reduction is added (softmax is unstabilized exp2 -> partials sum:
// O = (O1+O2)/(l1+l2)). 2 blocks/CU x 8 waves = 4 waves/SIMD (was 2), and
// per-wave dependent MFMA chains halve (PV depth 8 -> 4).
// Staging/swizzles are the r6/r7/r8 HW-verified formulas (8-wave variants).
// LDS unified (64 KB) so the epilogue reduce can alias the dead K/V buffers.
__global__ __launch_bounds__(512, 4) void attn(
    const bf16* __restrict__ Qb, const bf16* __restrict__ Kb,
    const bf16* __restrict__ Vt, bf16* __restrict__ Ob)
{
  __shared__ __align__(16) bf16 lds[32768];      // [K0|K1|V0|V1] 16 KB each
  const int t = threadIdx.x, lane = t & 63, wave = t >> 6;   // 8 waves
  const int l31 = lane & 31, hi = lane >> 5;
  const int qg = wave & 3, kh = wave >> 2;       // q-group, key-half
  const int bid = blockIdx.x;
  const int qt = (bid >> 3) & 15;
  const int bh = (bid & 7) * 4 + (bid >> 7);     // XCD-locality decode
  const size_t base = (size_t)bh * kS * kHD;
  const bf16* Qp = Qb + base + (size_t)qt * 128 * kHD;
  const bf16* Kp = Kb + base;
  const bf16* Vp = Vt + base;                     // [d][s]

  // Q fragments: B-operand of 32x32x16 (col=q=lane&31, k=hi*8+j, d-slice ks)
  bf16x8 qf[4];
#pragma unroll
  for (int ks = 0; ks < 4; ++ks)
    qf[ks] = *(const bf16x8*)(Qp + (size_t)(qg * 32 + l31) * kHD + ks * 16 + hi * 8);

  f32x16 oacc[2] = {};   // O^T partial (this key-half): row=d, col=q=lane&31
  float lsum = 0.f;

  // staging sources (pre-swizzled per-lane global addresses, rule 21; 8-wave form)
  const bf16* kst  = Kp + (size_t)(wave * 16 + (lane >> 3)) * kHD
                        + 8 * ((lane & 7) ^ (lane >> 3));
  const bf16* vst0 = Vp + (size_t)(wave * 8 + (lane >> 4)) * kS
                        + 8 * ((lane & 15) ^ (lane >> 4));
  const bf16* vst1 = Vp + (size_t)(wave * 8 + 4 + (lane >> 4)) * kS
                        + 8 * ((lane & 15) ^ (4 + (lane >> 4)));
  const int ldsb = wave * 1024;                   // elems; +512 for issue 1
  bf16* const kbase = lds;                        // K bufs at cur*8192
  bf16* const vbase = lds + 16384;                // V bufs at cur*8192

  // prologue: stage tile 0 into buf 0 (2 K-issues + 2 V-issues per wave)
  gl_lds16(kst,           kbase + ldsb);
  gl_lds16(kst + 8 * kHD, kbase + ldsb + 512);
  gl_lds16(vst0,          vbase + ldsb);
  gl_lds16(vst1,          vbase + ldsb + 512);

  int cur = 0;
  const int NT = kS / 128;
  for (int kt = 0; kt < NT; ++kt) {
    __syncthreads();   // vmcnt(0) drain: buf[cur] staged; prior reads of buf[cur^1] done
    if (kt + 1 < NT) {               // issue kt+1 DMA; in flight under all compute below
      const bf16* kn = kst + (size_t)(kt + 1) * 128 * kHD;
      const int vo = (kt + 1) * 128;
      gl_lds16(kn,           kbase + (cur ^ 1) * 8192 + ldsb);
      gl_lds16(kn + 8 * kHD, kbase + (cur ^ 1) * 8192 + ldsb + 512);
      gl_lds16(vst0 + vo,    vbase + (cur ^ 1) * 8192 + ldsb);
      gl_lds16(vst1 + vo,    vbase + (cur ^ 1) * 8192 + ldsb + 512);
    }
    const bf16* kbuf = kbase + cur * 8192;
    const bf16* vbuf = vbase + cur * 8192;

    // S^T[key][q] for this wave's 64-key half: 2 key-blocks x 4 d-slices
    f32x16 sacc[2] = {};
#pragma unroll
    for (int knb = 0; knb < 2; ++knb)
#pragma unroll
      for (int ks = 0; ks < 4; ++ks) {
        const bf16x8 kf = *(const bf16x8*)&kbuf[(kh * 64 + knb * 32 + l31) * 64
                                               + 8 * ((ks * 2 + hi) ^ (lane & 7))];
        sacc[knb] = MFMA32(kf, qf[ks], sacc[knb]);
      }

    // p = exp2(s); rowsum on VALU; pack to PV B-fragments (T12)
    bf16x8 pfrag[4];
#pragma unroll
    for (int knb = 0; knb < 2; ++knb) {
      float pe[16];
#pragma unroll
      for (int r = 0; r < 16; ++r) pe[r] = __builtin_amdgcn_exp2f(sacc[knb][r]);
      lsum += (((pe[0] + pe[1]) + (pe[2] + pe[3])) + ((pe[4] + pe[5]) + (pe[6] + pe[7])))
            + (((pe[8] + pe[9]) + (pe[10] + pe[11])) + ((pe[12] + pe[13]) + (pe[14] + pe[15])));
#pragma unroll
      for (int h2 = 0; h2 < 2; ++h2) {
        unsigned a0 = cvt_pk_bf16(pe[8 * h2 + 0], pe[8 * h2 + 1]);
        unsigned a1 = cvt_pk_bf16(pe[8 * h2 + 2], pe[8 * h2 + 3]);
        unsigned b0 = cvt_pk_bf16(pe[8 * h2 + 4], pe[8 * h2 + 5]);
        unsigned b1 = cvt_pk_bf16(pe[8 * h2 + 6], pe[8 * h2 + 7]);
        asm("v_permlane32_swap_b32 %0, %1" : "+v"(a0), "+v"(b0));
        asm("v_permlane32_swap_b32 %0, %1" : "+v"(a1), "+v"(b1));
        u32x4 w; w.x = a0; w.y = a1; w.z = b0; w.w = b1;
        pfrag[knb * 2 + h2] = __builtin_bit_cast(bf16x8, w);
      }
    }

    // O^T += V^T P over this key-half: slice index = kh*4+tt
#pragma unroll
    for (int nb = 0; nb < 2; ++nb)
#pragma unroll
      for (int tt = 0; tt < 4; ++tt) {
        const bf16x8 vf = *(const bf16x8*)&vbuf[(nb * 32 + l31) * 128
                                               + 8 * (((kh * 4 + tt) * 2 + hi) ^ (lane & 7))];
        oacc[nb] = MFMA32(vf, pfrag[tt], oacc[nb]);
      }
    cur ^= 1;
  }

  // ---- cross-wave key-half reduction (kh=1 dumps, kh=0 adds) ----
  __syncthreads();                 // all K/V reads done; alias lds freely
  float* red = (float*)lds;        // per (qg,lane): 36 f32, stride 144 B (16B-aligned)
  const int ridx = (qg * 64 + lane) * 36;
  if (kh) {
#pragma unroll
    for (int nb = 0; nb < 2; ++nb)
#pragma unroll
      for (int c = 0; c < 4; ++c) {
        f32x4 v4;
#pragma unroll
        for (int e = 0; e < 4; ++e) v4[e] = oacc[nb][c * 4 + e];
        *(f32x4*)&red[ridx + nb * 16 + c * 4] = v4;
      }
    red[ridx + 32] = lsum;
  }
  __syncthreads();
  if (kh == 0) {
#pragma unroll
    for (int nb = 0; nb < 2; ++nb)
#pragma unroll
      for (int c = 0; c < 4; ++c) {
        const f32x4 v4 = *(const f32x4*)&red[ridx + nb * 16 + c * 4];
#pragma unroll
        for (int e = 0; e < 4; ++e) oacc[nb][c * 4 + e] += v4[e];
      }
    lsum += red[ridx + 32];
    const float total = lsum + __shfl_xor(lsum, 32);
    const float inv = 1.0f / total;
    // per-wave transpose buffer at 40 KB offset (disjoint from red's 36.9 KB)
    bf16* tb = lds + 20480 + qg * 2304;           // [32 q][stride 72]
#pragma unroll
    for (int nb = 0; nb < 2; ++nb)
#pragma unroll
      for (int rq = 0; rq < 4; ++rq) {
        bf16x4 p4;
#pragma unroll
        for (int e = 0; e < 4; ++e) p4[e] = (bf16)(oacc[nb][rq * 4 + e] * inv);
        *(bf16x4*)&tb[l31 * 72 + nb * 32 + rq * 8 + hi * 4] = p4;
      }
    asm volatile("s_waitcnt lgkmcnt(0)" ::: "memory");
    const int b = bh >> 4, h = bh & 15;
    const int q = lane >> 1, hf = lane & 1;
    const bf16* srcl = &tb[q * 72 + hf * 32];
    bf16* dst = Ob + ((size_t)(b * kS + qt * 128 + qg * 32 + q)) * kD + h * kHD + hf * 32;
#pragma unroll
    for (int u = 0; u < 4; ++u)
      *(uint4*)(dst + u * 8) = *(const uint4*)(srcl + u * 8);
  }
}

// ---------------- output projection (fp32 epilogue) ----------------
__global__ __launch_bounds__(256, 4) void out_proj(
    const bf16* __restrict__ Ab, const bf16* __restrict__ wob, float* __restrict__ Cout)
{
  __shared__ __align__(16) bf16 smem[16384];   // 32 KB gemm dbuf
  const int m0 = blockIdx.x * 128, n0 = blockIdx.y * 128;
  f32x4 acc[4][4] = {};
  gemm_core_128(Ab, wob, m0, n0, kD, smem, acc);
  const int lane = threadIdx.x & 63, wave = threadIdx.x >> 6;
  const int wm = wave >> 1, wn = wave & 1, quad = lane >> 4, lc = lane & 15;
#pragma unroll
  for (int i = 0; i < 4; ++i)
#pragma unroll
    for (int r = 0; r < 4; ++r) {
      const int m = m0 + wm * 64 + i * 16 + quad * 4 + r;
#pragma unroll
      for (int j = 0; j < 4; ++j)
        Cout[(size_t)m * kD + n0 + wn * 64 + j * 16 + lc] = acc[i][j][r];
    }
}

extern "C" void kernel_launch(void* const* d_in, const int* in_sizes, int n_in,
                              void* d_out, int out_size, void* d_ws, size_t ws_size,
                              hipStream_t stream)
{
  const float* x  = (const float*)d_in[0];
  const float* wq = (const float*)d_in[1];
  const float* wk = (const float*)d_in[2];
  const float* wv = (const float*)d_in[3];
  const float* wo = (const float*)d_in[4];
  float* out = (float*)d_out;

  char* ws = (char*)d_ws;
  const size_t MB = 1024 * 1024;
  if (ws_size < 57 * MB) return;
  bf16* xb  = (bf16*)(ws + 0 * MB);   // 8 MB
  bf16* wqb = (bf16*)(ws + 8 * MB);   // 2 MB each
  bf16* wkb = (bf16*)(ws + 10 * MB);
  bf16* wvb = (bf16*)(ws + 12 * MB);
  bf16* wob = (bf16*)(ws + 14 * MB);
  bf16* Qb  = (bf16*)(ws + 16 * MB);  // 8 MB each, [B*H][S][64]
  bf16* Kb  = (bf16*)(ws + 24 * MB);
  bf16* Ob  = (bf16*)(ws + 40 * MB);  // 8 MB, [B,S,D]
  float2* rtab = (float2*)(ws + 48 * MB);  // 512 KB RoPE table
  bf16* Vtp = (bf16*)(ws + 49 * MB);  // 8 MB, V transposed [B*H][64][S]

  cvt_all<<<8448, 256, 0, stream>>>(x, wq, wk, wv, wo, xb, wqb, wkb, wvb, wob, rtab);
  proj_qkv<<<dim3(32, 8, 3), 256, 0, stream>>>(xb, wqb, wkb, wvb, Qb, Kb, Vtp, rtab);
  attn<<<dim3(512), 512, 0, stream>>>(Qb, Kb, Vtp, Ob);
  out_proj<<<dim3(32, 8), 256, 0, stream>>>(Ob, wob, out);
}